// Round 4
// baseline (689.041 us; speedup 1.0000x reference)
//
#include <hip/hip_runtime.h>
#include <hip/hip_bf16.h>

#define NN 50000      // nodes
#define NE 800000     // edges
#define DD 128        // hidden dim
#define NB 5          // GIN blocks
#define NG 512        // graphs
#define NC 10         // classes
#define BN_EPS 1e-5f
#define EPS1 129.0f   // 1 + eps_gin
#define GEMM_BLOCKS 391   // ceil(NN/128)

typedef __hip_bfloat16 bf16;
typedef __attribute__((ext_vector_type(8))) short short8;
typedef __attribute__((ext_vector_type(4))) float f32x4;

__device__ __forceinline__ float b2f(const bf16 v) { return __bfloat162float(v); }
__device__ __forceinline__ float us2f(unsigned int s) {
    return __uint_as_float((s & 0xffffu) << 16);
}
__device__ __forceinline__ unsigned pack2(float a, float b) {
    union { bf16 h; unsigned short u; } ua, ub;
    ua.h = __float2bfloat16(a); ub.h = __float2bfloat16(b);
    return ((unsigned)ub.u << 16) | (unsigned)ua.u;
}
__device__ __forceinline__ short f2bfs(float f) {
    union { bf16 h; short s; } u; u.h = __float2bfloat16(f); return u.s;
}

// ---- workspace layout (float offsets) ----
// all node-indexed buffers live in the PERMUTED (graph-sorted) domain
#define OFF_AGGH   0            // (free after fusion)
#define OFF_XF     3200000      // bf16 [NN,128]
#define OFF_H1     6400000      // bf16 [NN,128]  (GEMM1 out)
#define OFF_FEATS  9600000      // fp32 512*640
#define OFF_CSA    9927680      // 256 (parity-0 GEMM1 stats)
#define OFF_CSB    9927936      // 256 (parity-0 GEMM2 stats)
#define OFF_SC6    9928192      // 640
#define OFF_SH6    9928832      // 640
#define OFF_FLAGS  9929472      // 8 ints
#define OFF_PARAMS 9929480      // bf16 region
#define OFF_DEG    10055680     // int 50000
#define OFF_OFFS   10105680     // int 50001
#define OFF_ELIST  10155712     // int 800000
#define OFF_BDEG   10955712     // int 512
#define OFF_BOFFS  10956224     // int 513
#define OFF_RANK   10956800     // int 50000
#define OFF_PART   11006800     // int 64
#define OFF_ERANK  11006864     // int 800000 (per-edge rank within dst segment)
#define OFF_CS2    11806864     // 512: parity-1 csA [0:256), parity-1 csB [256:512)

// bf16 param region (bf16 element offsets)
#define P_W1T  0
#define P_W2T  81920
#define P_WC1  163840         // stored TRANSPOSED: [out_col 128][in_j 640]
#define P_B1   245760
#define P_G1   246400
#define P_BE1  247040
#define P_B2   247680
#define P_G2   248320
#define P_BE2  248960
#define P_BNG  249600
#define P_BNB  250240
#define P_BC1  250880
#define P_WC2  251008
#define P_BC2  252288

struct SmallSrc { const void* s[11]; };

// ---- dtype detection (also zeroes bdeg: runs before k_bhist) ----
__global__ void k_detect(const unsigned* __restrict__ xw, const int* __restrict__ eiw,
                         const int* __restrict__ bw, int* flags, int* __restrict__ bdeg) {
    __shared__ int sh[3];
    const int t = threadIdx.x;  // 256
    bdeg[t] = 0; bdeg[256 + t] = 0;
    if (t < 3) sh[t] = 0;
    __syncthreads();
    int c = 0;
    for (int i = 0; i < 16; i++) {
        unsigned w = xw[t * 16 + i];
        unsigned e = (w >> 7) & 0xff;
        c += (e >= 110 && e <= 131) ? 1 : 0;
    }
    atomicAdd(&sh[0], c);
    atomicAdd(&sh[1], (eiw[2 * t + 1] != 0) ? 1 : 0);
    atomicAdd(&sh[2], (bw[2 * t + 1] != 0) ? 1 : 0);
    __syncthreads();
    if (t == 0) {
        flags[0] = (sh[0] > 2048) ? 1 : 0;
        flags[1] = (sh[1] < 8) ? 1 : 0;
        flags[2] = (sh[2] < 8) ? 1 : 0;
    }
}

// ---- batch CSR; also zeroes deg (runs before k_hist) ----
__global__ void k_bhist(const int* __restrict__ flags, const int* __restrict__ batch,
                        int* __restrict__ bdeg, int* __restrict__ deg) {
    int n = blockIdx.x * 256 + threadIdx.x;
    if (n >= NN) return;
    deg[n] = 0;
    int g = flags[2] ? batch[2 * n] : batch[n];
    atomicAdd(&bdeg[g], 1);
}

__launch_bounds__(512)
__global__ void k_bscan(int* __restrict__ bdeg, int* __restrict__ boffs) {
    __shared__ int part[512];
    const int t = threadIdx.x;
    int d0 = bdeg[t];
    part[t] = d0;
    __syncthreads();
    for (int d = 1; d < 512; d <<= 1) {
        int v = (t >= d) ? part[t - d] : 0;
        __syncthreads();
        part[t] += v;
        __syncthreads();
    }
    int ex = part[t] - d0;
    boffs[t] = ex;
    bdeg[t] = ex;   // cursor
    if (t == 511) boffs[512] = part[511];
}

// rank[n] = permuted (graph-contiguous) id of old node n
__global__ void k_bplace(const int* __restrict__ flags, const int* __restrict__ batch,
                         int* __restrict__ bcur, int* __restrict__ rank) {
    int n = blockIdx.x * 256 + threadIdx.x;
    if (n >= NN) return;
    int g = flags[2] ? batch[2 * n] : batch[n];
    rank[n] = atomicAdd(&bcur[g], 1);
}

// x -> bf16 xfh in PERMUTED row order
__global__ void k_convert_x(const int* __restrict__ flags, const void* __restrict__ xr,
                            const int* __restrict__ rank, bf16* __restrict__ xfh) {
    int i = blockIdx.x * 256 + threadIdx.x;   // NN*DD/8 = 800000 chunks
    int r = i >> 4, seg = i & 15;
    uint4 o;
    if (flags[0]) {
        o = ((const uint4*)xr)[i];
    } else {
        float4 a = ((const float4*)xr)[2 * i], b = ((const float4*)xr)[2 * i + 1];
        o.x = pack2(a.x, a.y); o.y = pack2(a.z, a.w);
        o.z = pack2(b.x, b.y); o.w = pack2(b.z, b.w);
    }
    ((uint4*)xfh)[(long)rank[r] * 16 + seg] = o;
}

// unified param convert (Wc1 stored transposed for k_head)
__global__ void k_convert_params(const int* __restrict__ flags, const void* w1,
                                 const void* w2, const void* wc1, SmallSrc srcs,
                                 bf16* __restrict__ pb) {
    int i = blockIdx.x * 256 + threadIdx.x;
    if (i < 245760) {
        int which = i / 81920, j = i % 81920;
        const void* src = (which == 0) ? w1 : (which == 1) ? w2 : wc1;
        float v = flags[0] ? us2f(((const unsigned short*)src)[j]) : ((const float*)src)[j];
        if (which == 2) {
            int rowj = j >> 7, col = j & 127;      // Wc1 is [640][128]
            pb[P_WC1 + col * (NB * DD) + rowj] = __float2bfloat16(v);
        } else {
            int layer = j >> 14, rem = j & 16383;
            int k = rem >> 7, c = rem & 127;
            bf16* dst = pb + (which == 0 ? P_W1T : P_W2T);
            dst[(layer << 14) + c * DD + k] = __float2bfloat16(v);
        }
    } else {
        int j = i - 245760;
        if (j >= 6538) return;
        int seg, off;
        if (j < 5120)      { seg = j / 640; off = j - seg * 640; }
        else if (j < 5248) { seg = 8;  off = j - 5120; }
        else if (j < 6528) { seg = 9;  off = j - 5248; }
        else               { seg = 10; off = j - 6528; }
        const void* s = srcs.s[seg];
        float v = flags[0] ? us2f(((const unsigned short*)s)[off]) : ((const float*)s)[off];
        pb[P_B1 + j] = __float2bfloat16(v);
    }
}

// ---- edge CSR (permuted domain) ----
__global__ void k_hist(const int* __restrict__ flags, const int* __restrict__ ei,
                       const int* __restrict__ rank, int* __restrict__ deg,
                       int* __restrict__ erank) {
    int e = blockIdx.x * 256 + threadIdx.x;   // NE
    int d = flags[1] ? ei[2 * NE + 2 * e] : ei[NE + e];
    erank[e] = atomicAdd(&deg[rank[d]], 1);
}

__global__ void k_scan_part(const int* __restrict__ deg, int* __restrict__ part) {
    __shared__ int red[256];
    const int b = blockIdx.x, t = threadIdx.x;   // 49 x 256
    int i0 = b * 1024 + t * 4;
    int s = 0;
    if (i0 + 3 < NN) {
        int4 v = *(const int4*)(deg + i0);
        s = v.x + v.y + v.z + v.w;
    } else {
        for (int k = 0; k < 4; k++) if (i0 + k < NN) s += deg[i0 + k];
    }
    red[t] = s;
    __syncthreads();
    for (int d = 128; d > 0; d >>= 1) {
        if (t < d) red[t] += red[t + d];
        __syncthreads();
    }
    if (t == 0) part[b] = red[0];
}

__global__ void k_scan_apply(const int* __restrict__ deg, const int* __restrict__ part,
                             int* __restrict__ offs) {
    __shared__ int red[256];
    __shared__ int base_sh, total_sh;
    const int b = blockIdx.x, t = threadIdx.x;   // 49 x 256
    if (t < 64) {
        int v = (t < 49) ? part[t] : 0;
        int s = v;
        for (int d = 1; d < 64; d <<= 1) {
            int x = __shfl_up(s, d);
            if (t >= d) s += x;
        }
        if (t == b)  base_sh = s - v;
        if (t == 48) total_sh = s;
    }
    int i0 = b * 1024 + t * 4;
    int v[4]; int s = 0;
    #pragma unroll
    for (int k = 0; k < 4; k++) {
        int idx = i0 + k;
        v[k] = (idx < NN) ? deg[idx] : 0;
        s += v[k];
    }
    red[t] = s;
    __syncthreads();
    for (int d = 1; d < 256; d <<= 1) {
        int x = (t >= d) ? red[t - d] : 0;
        __syncthreads();
        red[t] += x;
        __syncthreads();
    }
    if (b == 0 && t == 0) offs[NN] = total_sh;
    int pre = base_sh + ((t == 0) ? 0 : red[t - 1]);
    #pragma unroll
    for (int k = 0; k < 4; k++) {
        int idx = i0 + k;
        if (idx < NN) { offs[idx] = pre; pre += v[k]; }
    }
}

// atomic-free placement; block 0 also zeroes csA parity-0 for the first fused GEMM
__global__ void k_place(const int* __restrict__ flags, const int* __restrict__ ei,
                        const int* __restrict__ rank, const int* __restrict__ offs,
                        const int* __restrict__ erank, int* __restrict__ elist,
                        float* __restrict__ csA0) {
    if (blockIdx.x == 0) csA0[threadIdx.x] = 0.f;   // 256 floats
    int e = blockIdx.x * 256 + threadIdx.x;   // NE
    int s, d;
    if (flags[1]) { s = ei[2 * e]; d = ei[2 * NE + 2 * e]; }
    else          { s = ei[e];     d = ei[NE + e]; }
    elist[offs[rank[d]] + erank[e]] = rank[s];
}

// pool body: per-graph sum of bn(xfh rows) -> feats[g][blk*128..]; NH = t>>6 range
template<int NH>
__device__ __forceinline__ void pool_body(int g, int t, const bf16* __restrict__ xfh,
                                          const int* __restrict__ boffs,
                                          const float* __restrict__ csB,
                                          const bf16* __restrict__ g2,
                                          const bf16* __restrict__ be2,
                                          float* __restrict__ feats_blk) {
    __shared__ float2 red[NH - 1][64];
    const int l = t & 63;    // col pair index
    const int h = t >> 6;    // row split
    const int lo = boffs[g], hi = boffs[g + 1];
    const unsigned* xw = (const unsigned*)xfh;
    float s0 = 0.f, s1 = 0.f;
    for (int n = lo + h; n < hi; n += NH) {
        unsigned p = xw[(long)n * 64 + l];
        s0 += us2f(p); s1 += us2f(p >> 16);
    }
    if (h) red[h - 1][l] = make_float2(s0, s1);
    __syncthreads();
    if (h == 0) {
        #pragma unroll
        for (int k = 0; k < NH - 1; k++) { s0 += red[k][l].x; s1 += red[k][l].y; }
        int c = l * 2;
        float mu0 = csB[c] * (1.f / NN);
        float var0 = csB[128 + c] * (1.f / NN) - mu0 * mu0;
        float sc0 = b2f(g2[c]) * rsqrtf(var0 + BN_EPS);
        float sh0 = b2f(be2[c]) - mu0 * sc0;
        float mu1 = csB[c + 1] * (1.f / NN);
        float var1 = csB[128 + c + 1] * (1.f / NN) - mu1 * mu1;
        float sc1 = b2f(g2[c + 1]) * rsqrtf(var1 + BN_EPS);
        float sh1 = b2f(be2[c + 1]) - mu1 * sc1;
        float cnt = (float)(hi - lo);
        float* fp = feats_blk + (long)g * (NB * DD) + c;
        fp[0] = sc0 * s0 + cnt * sh0;
        fp[1] = sc1 * s1 + cnt * sh1;
    }
}

// ---- FUSED gather + GEMM1 (+pool of layer i-1 in extra blocks) ----
// blocks [0,391): wave w gathers its 16 rows directly into the LDS A-tile
// (applying BN2 of layer i-1 inline), then MFMAs vs W1 — aggh never exists.
// blocks [391, 391+512): pool layer i-1.
// Stats plumbing (all cross-block deps ride dispatch boundaries):
//   csA_cur zeroed by PREVIOUS dispatch (k_place for i=0, GEMM2(i-1) else);
//   this kernel zeroes csB_cur (block 0) for GEMM2(i)'s accumulation.
#define WS_S 136
__launch_bounds__(512, 4)
__global__ void k_gather_gemm1(const int* __restrict__ offs, const int* __restrict__ elist,
                               const bf16* __restrict__ xfh,
                               const float* __restrict__ csBp,   // BN2 stats of layer i-1 (null for i=0)
                               const bf16* __restrict__ g2, const bf16* __restrict__ be2,
                               const bf16* __restrict__ W1T, const bf16* __restrict__ b1v,
                               bf16* __restrict__ Out, float* __restrict__ csA_out,
                               float* __restrict__ csB_zero,
                               const int* __restrict__ boffs, float* __restrict__ feats_prev) {
    if (blockIdx.x >= GEMM_BLOCKS) {
        if (feats_prev)
            pool_body<8>(blockIdx.x - GEMM_BLOCKS, threadIdx.x, xfh, boffs,
                         csBp, g2, be2, feats_prev);
        return;
    }
    __shared__ short Ws[128 * WS_S];   // W1T; reused as C staging
    __shared__ short As[128 * WS_S];   // gathered A-tile
    __shared__ float s_cs[256];
    const int t = threadIdx.x;
    const int row0 = blockIdx.x * 128;

    if (t < 256) {
        s_cs[t] = 0.f;
        if (blockIdx.x == 0) csB_zero[t] = 0.f;
    }
    {   // stage W1T (2048 uint4, 4 iters x 512 thr)
        const uint4* Wg = (const uint4*)W1T;
        #pragma unroll
        for (int i = 0; i < 4; i++) {
            int idx = i * 512 + t;
            *(uint4*)(&Ws[(idx >> 4) * WS_S + (idx & 15) * 8]) = Wg[idx];
        }
    }

    const int w = t >> 6;
    const int lane = t & 63;
    const int half = lane >> 5;        // which of 2 concurrent edges
    const int ql = lane & 31;          // uint2 column chunk (4 bf16 cols)
    const uint2* xw2 = (const uint2*)xfh;

    // hoist BN2 coefficients for this lane's 4 columns (reused over 16 nodes)
    float bsc[4], bsh[4];
    if (csBp) {
        int c = ql * 4;
        #pragma unroll
        for (int k = 0; k < 4; k++) {
            float mu = csBp[c + k] * (1.f / NN);
            float var = csBp[128 + c + k] * (1.f / NN) - mu * mu;
            bsc[k] = b2f(g2[c + k]) * rsqrtf(var + BN_EPS);
            bsh[k] = b2f(be2[c + k]) - mu * bsc[k];
        }
    }

    // ---- gather phase: wave w fills A-tile rows w*16 .. w*16+15 ----
    for (int k = 0; k < 16; k++) {
        const int n = row0 + w * 16 + k;
        float a0 = 0.f, a1 = 0.f, a2 = 0.f, a3 = 0.f;
        if (n < NN) {
            const int base = offs[n], end = offs[n + 1];
            {
                uint2 sp = xw2[(long)n * 32 + ql];
                float m = (half == 0) ? EPS1 : 0.f;
                a0 = m * us2f(sp.x); a1 = m * us2f(sp.x >> 16);
                a2 = m * us2f(sp.y); a3 = m * us2f(sp.y >> 16);
            }
            for (int i = base; i < end; i += 64) {
                int cnt = min(64, end - i);
                int e = (i + lane < end) ? elist[i + lane] : 0;
                int j = 0;
                for (; j + 16 <= cnt; j += 16) {       // 8 wave-loads = 16 edge rows
                    uint2 p[8];
                    #pragma unroll
                    for (int q = 0; q < 8; q++) {
                        int sj = __shfl(e, j + 2 * q + half);
                        p[q] = xw2[(long)sj * 32 + ql];
                    }
                    #pragma unroll
                    for (int q = 0; q < 8; q++) {
                        a0 += us2f(p[q].x); a1 += us2f(p[q].x >> 16);
                        a2 += us2f(p[q].y); a3 += us2f(p[q].y >> 16);
                    }
                }
                for (; j + 2 <= cnt; j += 2) {
                    int sj = __shfl(e, j + half);
                    uint2 p = xw2[(long)sj * 32 + ql];
                    a0 += us2f(p.x); a1 += us2f(p.x >> 16);
                    a2 += us2f(p.y); a3 += us2f(p.y >> 16);
                }
                if (j < cnt && half == 0) {            // odd tail: half 0 only
                    int sj = __shfl(e, j);
                    uint2 p = xw2[(long)sj * 32 + ql];
                    a0 += us2f(p.x); a1 += us2f(p.x >> 16);
                    a2 += us2f(p.y); a3 += us2f(p.y >> 16);
                }
            }
            a0 += __shfl_xor(a0, 32); a1 += __shfl_xor(a1, 32);
            a2 += __shfl_xor(a2, 32); a3 += __shfl_xor(a3, 32);
            if (csBp) {
                float fac = (float)(end - base) + EPS1;
                a0 = bsc[0] * a0 + fac * bsh[0];
                a1 = bsc[1] * a1 + fac * bsh[1];
                a2 = bsc[2] * a2 + fac * bsh[2];
                a3 = bsc[3] * a3 + fac * bsh[3];
            }
        }
        if (half == 0)
            *(uint2*)(&As[(w * 16 + k) * WS_S + ql * 4]) =
                make_uint2(pack2(a0, a1), pack2(a2, a3));
    }
    __syncthreads();   // As complete (own-wave rows) + Ws staged

    // ---- GEMM1 phase ----
    const int m = lane & 15;
    const int mh = lane >> 4;          // 0..3 k-chunk quarter
    short8 afrag[4];
    #pragma unroll
    for (int kk = 0; kk < 4; kk++)
        afrag[kk] = *(const short8*)(&As[(w * 16 + m) * WS_S + kk * 32 + mh * 8]);

    f32x4 acc[8];
    #pragma unroll
    for (int nt = 0; nt < 8; nt++) acc[nt] = (f32x4){0.f, 0.f, 0.f, 0.f};
    #pragma unroll
    for (int nt = 0; nt < 8; nt++) {
        const short* wrow = &Ws[(nt * 16 + m) * WS_S + mh * 8];
        #pragma unroll
        for (int kk = 0; kk < 4; kk++) {
            short8 b = *(const short8*)(wrow + kk * 32);
            acc[nt] = __builtin_amdgcn_mfma_f32_16x16x32_bf16(afrag[kk], b, acc[nt], 0, 0, 0);
        }
    }

    __syncthreads();               // all waves done reading Ws -> reuse as Cs
    short* Cs = Ws;
    #pragma unroll
    for (int nt = 0; nt < 8; nt++) {
        int col = nt * 16 + m;
        float bi = b2f(b1v[col]);
        float ps = 0.f, pq = 0.f;
        #pragma unroll
        for (int reg = 0; reg < 4; reg++) {
            int rr = row0 + w * 16 + mh * 4 + reg;
            float o = fmaxf(acc[nt][reg] + bi, 0.f);
            Cs[(w * 16 + mh * 4 + reg) * WS_S + col] = f2bfs(o);
            if (rr < NN) { ps += o; pq += o * o; }
        }
        ps += __shfl_xor(ps, 16); ps += __shfl_xor(ps, 32);
        pq += __shfl_xor(pq, 16); pq += __shfl_xor(pq, 32);
        if (mh == 0) {
            atomicAdd(&s_cs[col], ps);
            atomicAdd(&s_cs[128 + col], pq);
        }
    }
    __syncthreads();
    #pragma unroll
    for (int i = 0; i < 4; i++) {
        int idx = i * 512 + t;
        int row = idx >> 4, seg = idx & 15;
        int rr = row0 + row;
        if (rr < NN)
            *(uint4*)(Out + (long)rr * DD + seg * 8) = *(uint4*)(&Cs[row * WS_S + seg * 8]);
    }
    if (t < 256) atomicAdd(&csA_out[t], s_cs[t]);
}

// standalone pool for the last layer
__launch_bounds__(256)
__global__ void k_pool(const bf16* __restrict__ xfh, const int* __restrict__ boffs,
                       const float* __restrict__ csB, const bf16* __restrict__ g2,
                       const bf16* __restrict__ be2, float* __restrict__ feats_blk) {
    pool_body<4>(blockIdx.x, threadIdx.x, xfh, boffs, csB, g2, be2, feats_blk);
}

// ---- MFMA GEMM (GEMM2): 512 threads, 128 rows/block ----
__launch_bounds__(512)
__global__ void k_gemm_mfma(const bf16* __restrict__ A, const bf16* __restrict__ WT,
                            const bf16* __restrict__ bias,
                            const float* __restrict__ bn_cs, const bf16* __restrict__ bn_g,
                            const bf16* __restrict__ bn_be,
                            bf16* __restrict__ Out, float* __restrict__ cs_out,
                            float* cs_zero) {
    __shared__ short Ws[128 * WS_S];   // 34816 B (reused as C-staging)
    __shared__ float s_cs[256];
    __shared__ float s_sc[DD], s_sh[DD];
    const int t = threadIdx.x;
    const int row0 = blockIdx.x * 128;

    if (t < 256) {
        if (cs_zero && blockIdx.x == 0) cs_zero[t] = 0.f;
        s_cs[t] = 0.f;
    }
    if (bn_cs && t < DD) {
        float mu = bn_cs[t] * (1.f / NN);
        float var = bn_cs[128 + t] * (1.f / NN) - mu * mu;
        float sc = b2f(bn_g[t]) * rsqrtf(var + BN_EPS);
        s_sc[t] = sc;
        s_sh[t] = b2f(bn_be[t]) - mu * sc;
    }
    {   // stage WT (2048 uint4, 4 iters x 512 thr)
        const uint4* Wg = (const uint4*)WT;
        #pragma unroll
        for (int i = 0; i < 4; i++) {
            int idx = i * 512 + t;
            int row = idx >> 4, seg = idx & 15;
            *(uint4*)(&Ws[row * WS_S + seg * 8]) = Wg[idx];
        }
    }
    __syncthreads();

    const int w = t >> 6;          // wave 0..7 -> rows w*16..+15
    const int lane = t & 63;
    const int m = lane & 15;
    const int half = lane >> 4;
    const int r = row0 + w * 16 + m;

    short8 afrag[4];
    if (r < NN) {
        #pragma unroll
        for (int kk = 0; kk < 4; kk++)
            afrag[kk] = *(const short8*)(A + (long)r * DD + kk * 32 + half * 8);
        if (bn_cs) {
            #pragma unroll
            for (int kk = 0; kk < 4; kk++) {
                int c0 = kk * 32 + half * 8;
                uint4 p = *(uint4*)&afrag[kk];
                float v0 = us2f(p.x) * s_sc[c0+0] + s_sh[c0+0];
                float v1 = us2f(p.x >> 16) * s_sc[c0+1] + s_sh[c0+1];
                float v2 = us2f(p.y) * s_sc[c0+2] + s_sh[c0+2];
                float v3 = us2f(p.y >> 16) * s_sc[c0+3] + s_sh[c0+3];
                float v4 = us2f(p.z) * s_sc[c0+4] + s_sh[c0+4];
                float v5 = us2f(p.z >> 16) * s_sc[c0+5] + s_sh[c0+5];
                float v6 = us2f(p.w) * s_sc[c0+6] + s_sh[c0+6];
                float v7 = us2f(p.w >> 16) * s_sc[c0+7] + s_sh[c0+7];
                p.x = pack2(v0, v1); p.y = pack2(v2, v3);
                p.z = pack2(v4, v5); p.w = pack2(v6, v7);
                afrag[kk] = *(short8*)&p;
            }
        }
    } else {
        #pragma unroll
        for (int kk = 0; kk < 4; kk++) afrag[kk] = (short8){0,0,0,0,0,0,0,0};
    }

    f32x4 acc[8];
    #pragma unroll
    for (int nt = 0; nt < 8; nt++) acc[nt] = (f32x4){0.f, 0.f, 0.f, 0.f};

    #pragma unroll
    for (int nt = 0; nt < 8; nt++) {
        const short* wrow = &Ws[(nt * 16 + m) * WS_S + half * 8];
        #pragma unroll
        for (int kk = 0; kk < 4; kk++) {
            short8 b = *(const short8*)(wrow + kk * 32);
            acc[nt] = __builtin_amdgcn_mfma_f32_16x16x32_bf16(afrag[kk], b, acc[nt], 0, 0, 0);
        }
    }

    __syncthreads();               // all waves done reading Ws -> reuse as Cs
    short* Cs = Ws;
    #pragma unroll
    for (int nt = 0; nt < 8; nt++) {
        int col = nt * 16 + m;
        float bi = b2f(bias[col]);
        float ps = 0.f, pq = 0.f;
        #pragma unroll
        for (int reg = 0; reg < 4; reg++) {
            int rr = row0 + w * 16 + half * 4 + reg;
            float o = fmaxf(acc[nt][reg] + bi, 0.f);
            Cs[(w * 16 + half * 4 + reg) * WS_S + col] = f2bfs(o);
            if (rr < NN) { ps += o; pq += o * o; }
        }
        ps += __shfl_xor(ps, 16); ps += __shfl_xor(ps, 32);
        pq += __shfl_xor(pq, 16); pq += __shfl_xor(pq, 32);
        if (half == 0) {
            atomicAdd(&s_cs[col], ps);
            atomicAdd(&s_cs[128 + col], pq);
        }
    }
    __syncthreads();
    #pragma unroll
    for (int i = 0; i < 4; i++) {
        int idx = i * 512 + t;
        int row = idx >> 4, seg = idx & 15;
        int rr = row0 + row;
        if (rr < NN)
            *(uint4*)(Out + (long)rr * DD + seg * 8) = *(uint4*)(&Cs[row * WS_S + seg * 8]);
    }
    if (t < 256) atomicAdd(&cs_out[t], s_cs[t]);
}

// parallel feature stats: 20 blocks x 256 thr (32 cols x 8 g-groups)
__launch_bounds__(256)
__global__ void k_feat_stats(const float* __restrict__ feats, const bf16* __restrict__ bn_g,
                             const bf16* __restrict__ bn_b, float* __restrict__ sc6,
                             float* __restrict__ sh6) {
    __shared__ float rs[8][32], rq[8][32];
    const int j0 = blockIdx.x * 32;
    const int jl = threadIdx.x & 31, gg = threadIdx.x >> 5;
    float s = 0.f, q = 0.f;
    for (int g = gg; g < NG; g += 8) {
        float v = feats[(long)g * (NB * DD) + j0 + jl];
        s += v; q += v * v;
    }
    rs[gg][jl] = s; rq[gg][jl] = q;
    __syncthreads();
    if (gg == 0) {
        #pragma unroll
        for (int k = 1; k < 8; k++) { s += rs[k][jl]; q += rq[k][jl]; }
        int j = j0 + jl;
        float mu = s / NG;
        float var = q / NG - mu * mu;
        float sc = b2f(bn_g[j]) * rsqrtf(var + BN_EPS);
        sc6[j] = sc;
        sh6[j] = b2f(bn_b[j]) - mu * sc;
    }
}

__launch_bounds__(128)
__global__ void k_head(const int* __restrict__ flags, const float* __restrict__ feats,
                       const float* __restrict__ sc6, const float* __restrict__ sh6,
                       const bf16* __restrict__ Wc1T, const bf16* __restrict__ bc1,
                       const bf16* __restrict__ Wc2, const bf16* __restrict__ bc2,
                       void* out) {
    __shared__ float fs[NB * DD];
    __shared__ float f1[DD];
    __shared__ float lg[NC + 2];
    const int g = blockIdx.x, t = threadIdx.x;
    for (int j = t; j < NB * DD; j += 128)
        fs[j] = feats[(long)g * (NB * DD) + j] * sc6[j] + sh6[j];
    __syncthreads();
    float acc = b2f(bc1[t]);
    {   // Wc1T row t: 640 contiguous bf16 = 80 x short8
        const short8* wr = (const short8*)(Wc1T + (long)t * (NB * DD));
        #pragma unroll 4
        for (int jb = 0; jb < 80; jb++) {
            short8 wv = wr[jb];
            uint4 p = *(uint4*)&wv;
            float4 f0 = *(const float4*)&fs[jb * 8];
            float4 f1v = *(const float4*)&fs[jb * 8 + 4];
            acc += f0.x * us2f(p.x) + f0.y * us2f(p.x >> 16)
                 + f0.z * us2f(p.y) + f0.w * us2f(p.y >> 16)
                 + f1v.x * us2f(p.z) + f1v.y * us2f(p.z >> 16)
                 + f1v.z * us2f(p.w) + f1v.w * us2f(p.w >> 16);
        }
    }
    f1[t] = fmaxf(acc, 0.f);
    __syncthreads();
    if (t < NC) {
        float a = b2f(bc2[t]);
        for (int k = 0; k < DD; k++) a += f1[k] * b2f(Wc2[k * NC + t]);
        lg[t] = a;
    }
    __syncthreads();
    if (t == 0) {
        float m = -1e30f;
        for (int c = 0; c < NC; c++) m = fmaxf(m, lg[c]);
        float s = 0.f;
        for (int c = 0; c < NC; c++) s += expf(lg[c] - m);
        lg[NC] = m + logf(s);
    }
    __syncthreads();
    if (t < NC) {
        float val = lg[t] - lg[NC];
        if (flags[0]) ((bf16*)out)[g * NC + t] = __float2bfloat16(val);
        else          ((float*)out)[g * NC + t] = val;
    }
}

extern "C" void kernel_launch(void* const* d_in, const int* in_sizes, int n_in,
                              void* d_out, int out_size, void* d_ws, size_t ws_size,
                              hipStream_t stream) {
    const void* x     = d_in[0];
    const int*  ei    = (const int*)d_in[1];
    const int*  batch = (const int*)d_in[2];

    float* ws    = (float*)d_ws;
    bf16*  xfh   = (bf16*)(ws + OFF_XF);
    bf16*  h1h   = (bf16*)(ws + OFF_H1);
    float* feats = ws + OFF_FEATS;
    float* sc6   = ws + OFF_SC6;
    float* sh6   = ws + OFF_SH6;
    int*   flags = (int*)(ws + OFF_FLAGS);
    bf16*  pb    = (bf16*)(ws + OFF_PARAMS);
    int*   deg   = (int*)(ws + OFF_DEG);
    int*   offs  = (int*)(ws + OFF_OFFS);
    int*   elist = (int*)(ws + OFF_ELIST);
    int*   bdeg  = (int*)(ws + OFF_BDEG);
    int*   boffs = (int*)(ws + OFF_BOFFS);
    int*   rank  = (int*)(ws + OFF_RANK);
    int*   part  = (int*)(ws + OFF_PART);
    int*   erank = (int*)(ws + OFF_ERANK);

    float* csA_buf[2] = { ws + OFF_CSA, ws + OFF_CS2 };
    float* csB_buf[2] = { ws + OFF_CSB, ws + OFF_CS2 + 256 };

    bf16 *pW1T = pb + P_W1T, *pW2T = pb + P_W2T, *pWc1 = pb + P_WC1;
    bf16 *pb1 = pb + P_B1, *pg1 = pb + P_G1, *pbe1 = pb + P_BE1;
    bf16 *pb2 = pb + P_B2, *pg2 = pb + P_G2, *pbe2 = pb + P_BE2;
    bf16 *pbng = pb + P_BNG, *pbnb = pb + P_BNB;
    bf16 *pbc1 = pb + P_BC1, *pWc2 = pb + P_WC2, *pbc2 = pb + P_BC2;

    k_detect<<<1, 256, 0, stream>>>((const unsigned*)x, ei, batch, flags, bdeg);

    k_bhist<<<(NN + 255) / 256, 256, 0, stream>>>(flags, batch, bdeg, deg);
    k_bscan<<<1, 512, 0, stream>>>(bdeg, boffs);
    k_bplace<<<(NN + 255) / 256, 256, 0, stream>>>(flags, batch, bdeg, rank);

    k_convert_x<<<NN * DD / 8 / 256, 256, 0, stream>>>(flags, x, rank, xfh);

    SmallSrc ss;
    ss.s[0] = d_in[4];  ss.s[1] = d_in[5];  ss.s[2] = d_in[6];
    ss.s[3] = d_in[8];  ss.s[4] = d_in[9];  ss.s[5] = d_in[10];
    ss.s[6] = d_in[11]; ss.s[7] = d_in[12];
    ss.s[8] = d_in[14]; ss.s[9] = d_in[15]; ss.s[10] = d_in[16];
    k_convert_params<<<(245760 + 6538 + 255) / 256, 256, 0, stream>>>(
        flags, d_in[3], d_in[7], d_in[13], ss, pb);

    k_hist<<<NE / 256, 256, 0, stream>>>(flags, ei, rank, deg, erank);
    k_scan_part<<<49, 256, 0, stream>>>(deg, part);
    k_scan_apply<<<49, 256, 0, stream>>>(deg, part, offs);
    k_place<<<NE / 256, 256, 0, stream>>>(flags, ei, rank, offs, erank, elist,
                                          csA_buf[0]);

    for (int i = 0; i < NB; i++) {
        // fused gather+GEMM1 (+pool of layer i-1): stats1 -> csA[i&1]
        // (pre-zeroed by previous dispatch), zeroes csB[i&1] for GEMM2.
        k_gather_gemm1<<<GEMM_BLOCKS + NG, 512, 0, stream>>>(
            offs, elist, xfh,
            (i == 0) ? nullptr : csB_buf[(i - 1) & 1],
            pg2 + (i - 1) * DD, pbe2 + (i - 1) * DD,
            pW1T + i * DD * DD, pb1 + i * DD,
            h1h, csA_buf[i & 1], csB_buf[i & 1],
            boffs, (i == 0) ? nullptr : feats + (i - 1) * DD);
        // GEMM2: bn1(h1h) -> xfh, stats -> csB[i&1], zero csA[(i+1)&1]
        k_gemm_mfma<<<GEMM_BLOCKS, 512, 0, stream>>>(
            h1h, pW2T + i * DD * DD, pb2 + i * DD,
            csA_buf[i & 1], pg1 + i * DD, pbe1 + i * DD,
            xfh, csB_buf[i & 1],
            (i < NB - 1) ? csA_buf[(i + 1) & 1] : nullptr);
    }
    // final layer pool (layer NB-1 stats live in csB[(NB-1)&1] = csB[0])
    k_pool<<<NG, 256, 0, stream>>>(xfh, boffs, csB_buf[(NB - 1) & 1],
                                   pg2 + (NB - 1) * DD, pbe2 + (NB - 1) * DD,
                                   feats + (NB - 1) * DD);

    k_feat_stats<<<20, 256, 0, stream>>>(feats, pbng, pbnb, sc6, sh6);
    k_head<<<NG, 128, 0, stream>>>(flags, feats, sc6, sh6, pWc1, pbc1, pWc2, pbc2, d_out);
}

// Round 7
// 646.312 us; speedup vs baseline: 1.0661x; 1.0661x over previous
//
#include <hip/hip_runtime.h>
#include <hip/hip_bf16.h>

#define NN 50000      // nodes
#define NE 800000     // edges
#define DD 128        // hidden dim
#define NB 5          // GIN blocks
#define NG 512        // graphs
#define NC 10         // classes
#define BN_EPS 1e-5f
#define EPS1 129.0f   // 1 + eps_gin
#define GATHER_BLOCKS 12500   // NN/4
#define NXCD 8

typedef __hip_bfloat16 bf16;
typedef __attribute__((ext_vector_type(8))) short short8;
typedef __attribute__((ext_vector_type(4))) float f32x4;

__device__ __forceinline__ float b2f(const bf16 v) { return __bfloat162float(v); }
__device__ __forceinline__ float us2f(unsigned int s) {
    return __uint_as_float((s & 0xffffu) << 16);
}
__device__ __forceinline__ unsigned pack2(float a, float b) {
    union { bf16 h; unsigned short u; } ua, ub;
    ua.h = __float2bfloat16(a); ub.h = __float2bfloat16(b);
    return ((unsigned)ub.u << 16) | (unsigned)ua.u;
}
__device__ __forceinline__ short f2bfs(float f) {
    union { bf16 h; short s; } u; u.h = __float2bfloat16(f); return u.s;
}

// ---- workspace layout (float offsets) ----
#define OFF_AGGH   0            // bf16 [NN,128]
#define OFF_XF     3200000      // bf16 [NN,128]
#define OFF_H1     6400000      // bf16 [NN,128]
#define OFF_FEATS  9600000      // fp32 512*640
#define OFF_CSA    9927680      // 256: sum[0:128), sumsq[128:256)
#define OFF_CSB    9927936      // 256
#define OFF_SC6    9928192      // 640
#define OFF_SH6    9928832      // 640
#define OFF_FLAGS  9929472      // 8 ints
#define OFF_PARAMS 9929480      // bf16 region
#define OFF_DEG    10055680     // int 50000
#define OFF_OFFS   10105680     // int 50001
#define OFF_ELIST  10155712     // int 800000
#define OFF_BDEG   10955712     // int 512
#define OFF_BOFFS  10956224     // int 513
#define OFF_RANK   10956800     // int 50000
#define OFF_PART   11006800     // int 64
#define OFF_ERANK  11006864     // int 800000 (per-edge rank within dst segment)

// bf16 param region (bf16 element offsets)
#define P_W1T  0
#define P_W2T  81920
#define P_WC1  163840         // stored TRANSPOSED: [out_col 128][in_j 640]
#define P_B1   245760
#define P_G1   246400
#define P_BE1  247040
#define P_B2   247680
#define P_G2   248320
#define P_BE2  248960
#define P_BNG  249600
#define P_BNB  250240
#define P_BC1  250880
#define P_WC2  251008
#define P_BC2  252288

#define N_BIGPAR   245760
#define N_SMALLPAR 6538
#define CVX_BLOCKS 3125   // 800000/256 (x-convert portion)
#define CVP_BLOCKS ((N_BIGPAR + N_SMALLPAR + 255) / 256)   // = 986 (param portion)

struct SmallSrc { const void* s[11]; };

// ---- dtype detection (also zeroes bdeg: runs before k_bhist) ----
__global__ void k_detect(const unsigned* __restrict__ xw, const int* __restrict__ eiw,
                         const int* __restrict__ bw, int* flags, int* __restrict__ bdeg) {
    __shared__ int sh[3];
    const int t = threadIdx.x;  // 256
    bdeg[t] = 0; bdeg[256 + t] = 0;
    if (t < 3) sh[t] = 0;
    __syncthreads();
    int c = 0;
    for (int i = 0; i < 16; i++) {
        unsigned w = xw[t * 16 + i];
        unsigned e = (w >> 7) & 0xff;
        c += (e >= 110 && e <= 131) ? 1 : 0;
    }
    atomicAdd(&sh[0], c);
    atomicAdd(&sh[1], (eiw[2 * t + 1] != 0) ? 1 : 0);
    atomicAdd(&sh[2], (bw[2 * t + 1] != 0) ? 1 : 0);
    __syncthreads();
    if (t == 0) {
        flags[0] = (sh[0] > 2048) ? 1 : 0;
        flags[1] = (sh[1] < 8) ? 1 : 0;
        flags[2] = (sh[2] < 8) ? 1 : 0;
    }
}

// ---- batch CSR; also zeroes deg (runs before k_hist) ----
__global__ void k_bhist(const int* __restrict__ flags, const int* __restrict__ batch,
                        int* __restrict__ bdeg, int* __restrict__ deg) {
    int n = blockIdx.x * 256 + threadIdx.x;
    if (n >= NN) return;
    deg[n] = 0;
    int g = flags[2] ? batch[2 * n] : batch[n];
    atomicAdd(&bdeg[g], 1);
}

__launch_bounds__(512)
__global__ void k_bscan(int* __restrict__ bdeg, int* __restrict__ boffs) {
    __shared__ int part[512];
    const int t = threadIdx.x;
    int d0 = bdeg[t];
    part[t] = d0;
    __syncthreads();
    for (int d = 1; d < 512; d <<= 1) {
        int v = (t >= d) ? part[t - d] : 0;
        __syncthreads();
        part[t] += v;
        __syncthreads();
    }
    int ex = part[t] - d0;
    boffs[t] = ex;
    bdeg[t] = ex;   // cursor
    if (t == 511) boffs[512] = part[511];
}

// rank[n] = permuted (graph-contiguous) id of old node n
__global__ void k_bplace(const int* __restrict__ flags, const int* __restrict__ batch,
                         int* __restrict__ bcur, int* __restrict__ rank) {
    int n = blockIdx.x * 256 + threadIdx.x;
    if (n >= NN) return;
    int g = flags[2] ? batch[2 * n] : batch[n];
    rank[n] = atomicAdd(&bcur[g], 1);
}

// merged: x -> bf16 xfh (permuted rows)  +  all param conversion
__global__ void k_convert_all(const int* __restrict__ flags, const void* __restrict__ xr,
                              const int* __restrict__ rank, bf16* __restrict__ xfh,
                              const void* w1, const void* w2, const void* wc1,
                              SmallSrc srcs, bf16* __restrict__ pb) {
    if (blockIdx.x < CVX_BLOCKS) {
        int i = blockIdx.x * 256 + threadIdx.x;   // NN*DD/8 = 800000 chunks
        int r = i >> 4, seg = i & 15;
        uint4 o;
        if (flags[0]) {
            o = ((const uint4*)xr)[i];
        } else {
            float4 a = ((const float4*)xr)[2 * i], b = ((const float4*)xr)[2 * i + 1];
            o.x = pack2(a.x, a.y); o.y = pack2(a.z, a.w);
            o.z = pack2(b.x, b.y); o.w = pack2(b.z, b.w);
        }
        ((uint4*)xfh)[(long)rank[r] * 16 + seg] = o;
        return;
    }
    int i = (blockIdx.x - CVX_BLOCKS) * 256 + threadIdx.x;
    if (i < N_BIGPAR) {
        int which = i / 81920, j = i % 81920;
        const void* src = (which == 0) ? w1 : (which == 1) ? w2 : wc1;
        float v = flags[0] ? us2f(((const unsigned short*)src)[j]) : ((const float*)src)[j];
        if (which == 2) {
            int rowj = j >> 7, col = j & 127;      // Wc1 is [640][128]
            pb[P_WC1 + col * (NB * DD) + rowj] = __float2bfloat16(v);
        } else {
            int layer = j >> 14, rem = j & 16383;
            int k = rem >> 7, c = rem & 127;
            bf16* dst = pb + (which == 0 ? P_W1T : P_W2T);
            dst[(layer << 14) + c * DD + k] = __float2bfloat16(v);
        }
    } else {
        int j = i - N_BIGPAR;
        if (j >= N_SMALLPAR) return;
        int seg, off;
        if (j < 5120)      { seg = j / 640; off = j - seg * 640; }
        else if (j < 5248) { seg = 8;  off = j - 5120; }
        else if (j < 6528) { seg = 9;  off = j - 5248; }
        else               { seg = 10; off = j - 6528; }
        const void* s = srcs.s[seg];
        float v = flags[0] ? us2f(((const unsigned short*)s)[off]) : ((const float*)s)[off];
        pb[P_B1 + j] = __float2bfloat16(v);
    }
}

// ---- edge CSR (permuted domain) ----
__global__ void k_hist(const int* __restrict__ flags, const int* __restrict__ ei,
                       const int* __restrict__ rank, int* __restrict__ deg,
                       int* __restrict__ erank) {
    int e = blockIdx.x * 256 + threadIdx.x;   // NE
    int d = flags[1] ? ((const int2*)ei)[NE + e].x : ei[NE + e];
    erank[e] = atomicAdd(&deg[rank[d]], 1);
}

__global__ void k_scan_part(const int* __restrict__ deg, int* __restrict__ part) {
    __shared__ int red[256];
    const int b = blockIdx.x, t = threadIdx.x;   // 49 x 256
    int i0 = b * 1024 + t * 4;
    int s = 0;
    if (i0 + 3 < NN) {
        int4 v = *(const int4*)(deg + i0);
        s = v.x + v.y + v.z + v.w;
    } else {
        for (int k = 0; k < 4; k++) if (i0 + k < NN) s += deg[i0 + k];
    }
    red[t] = s;
    __syncthreads();
    for (int d = 128; d > 0; d >>= 1) {
        if (t < d) red[t] += red[t + d];
        __syncthreads();
    }
    if (t == 0) part[b] = red[0];
}

__global__ void k_scan_apply(const int* __restrict__ deg, const int* __restrict__ part,
                             int* __restrict__ offs) {
    __shared__ int red[256];
    __shared__ int base_sh, total_sh;
    const int b = blockIdx.x, t = threadIdx.x;   // 49 x 256
    if (t < 64) {
        int v = (t < 49) ? part[t] : 0;
        int s = v;
        for (int d = 1; d < 64; d <<= 1) {
            int x = __shfl_up(s, d);
            if (t >= d) s += x;
        }
        if (t == b)  base_sh = s - v;
        if (t == 48) total_sh = s;
    }
    int i0 = b * 1024 + t * 4;
    int v[4]; int s = 0;
    #pragma unroll
    for (int k = 0; k < 4; k++) {
        int idx = i0 + k;
        v[k] = (idx < NN) ? deg[idx] : 0;
        s += v[k];
    }
    red[t] = s;
    __syncthreads();
    for (int d = 1; d < 256; d <<= 1) {
        int x = (t >= d) ? red[t - d] : 0;
        __syncthreads();
        red[t] += x;
        __syncthreads();
    }
    if (b == 0 && t == 0) offs[NN] = total_sh;
    int pre = base_sh + ((t == 0) ? 0 : red[t - 1]);
    #pragma unroll
    for (int k = 0; k < 4; k++) {
        int idx = i0 + k;
        if (idx < NN) { offs[idx] = pre; pre += v[k]; }
    }
}

// atomic-free placement: slot = offs[rank[d]] + erank[e]
__global__ void k_place(const int* __restrict__ flags, const int* __restrict__ ei,
                        const int* __restrict__ rank, const int* __restrict__ offs,
                        const int* __restrict__ erank, int* __restrict__ elist) {
    int e = blockIdx.x * 256 + threadIdx.x;   // NE
    int s, d;
    if (flags[1]) { s = ((const int2*)ei)[e].x; d = ((const int2*)ei)[NE + e].x; }
    else          { s = ei[e];                  d = ei[NE + e]; }
    elist[offs[rank[d]] + erank[e]] = rank[s];
}

// pool body: per-graph sum of bn(xfh rows) -> feats[g][blk*128..]
__device__ __forceinline__ void pool_body(int g, int t, const bf16* __restrict__ xfh,
                                          const int* __restrict__ boffs,
                                          const float* __restrict__ csB,
                                          const bf16* __restrict__ g2,
                                          const bf16* __restrict__ be2,
                                          float* __restrict__ feats_blk) {
    __shared__ float2 red[3][64];
    const int l = t & 63;    // col pair index
    const int h = t >> 6;    // 0..3 row split
    const int lo = boffs[g], hi = boffs[g + 1];
    const unsigned* xw = (const unsigned*)xfh;
    float s0 = 0.f, s1 = 0.f;
    for (int n = lo + h; n < hi; n += 4) {
        unsigned p = xw[(long)n * 64 + l];
        s0 += us2f(p); s1 += us2f(p >> 16);
    }
    if (h) red[h - 1][l] = make_float2(s0, s1);
    __syncthreads();
    if (h == 0) {
        s0 += red[0][l].x + red[1][l].x + red[2][l].x;
        s1 += red[0][l].y + red[1][l].y + red[2][l].y;
        int c = l * 2;
        float mu0 = csB[c] * (1.f / NN);
        float var0 = csB[128 + c] * (1.f / NN) - mu0 * mu0;
        float sc0 = b2f(g2[c]) * rsqrtf(var0 + BN_EPS);
        float sh0 = b2f(be2[c]) - mu0 * sc0;
        float mu1 = csB[c + 1] * (1.f / NN);
        float var1 = csB[128 + c + 1] * (1.f / NN) - mu1 * mu1;
        float sc1 = b2f(g2[c + 1]) * rsqrtf(var1 + BN_EPS);
        float sh1 = b2f(be2[c + 1]) - mu1 * sc1;
        float cnt = (float)(hi - lo);
        float* fp = feats_blk + (long)g * (NB * DD) + c;
        fp[0] = sc0 * s0 + cnt * sh0;
        fp[1] = sc1 * s1 + cnt * sh1;
    }
}

// combined: blocks [0,12500) gather layer i; blocks [12500,13012) pool layer i-1.
// Gather v2 (proven numerics): uint2 lanes — 32 lanes cover a 256B row, two
// edge slots per wave (half = lane>>5). XCD-aware bijective block swizzle:
// round-robin dispatch -> contiguous node chunks per XCD, so each graph's
// ~25KB row window lives in ONE per-XCD L2 (speed-only; values unchanged).
__global__ void k_gather_pool(const int* __restrict__ offs, const int* __restrict__ elist,
                              const bf16* __restrict__ xfh, bf16* __restrict__ aggh,
                              const float* __restrict__ csB, const bf16* __restrict__ g2,
                              const bf16* __restrict__ be2, float* __restrict__ csA_zero,
                              const int* __restrict__ boffs, float* __restrict__ feats_prev) {
    if (blockIdx.x >= GATHER_BLOCKS) {
        if (feats_prev)
            pool_body(blockIdx.x - GATHER_BLOCKS, threadIdx.x, xfh, boffs,
                      csB, g2, be2, feats_prev);
        return;
    }
    if (blockIdx.x == 0) csA_zero[threadIdx.x] = 0.f;   // 256 floats
    // bijective XCD swizzle (GATHER_BLOCKS = 8*1562 + 4)
    int blk;
    {
        const int q = GATHER_BLOCKS / NXCD, r = GATHER_BLOCKS % NXCD;
        int xcd = blockIdx.x % NXCD, pos = blockIdx.x / NXCD;
        blk = (xcd < r) ? xcd * (q + 1) + pos : r * (q + 1) + (xcd - r) * q + pos;
    }
    const int w = threadIdx.x >> 6;
    const int lane = threadIdx.x & 63;
    const int half = lane >> 5;        // which of 2 concurrent edges
    const int ql = lane & 31;          // uint2 column chunk (4 bf16 cols)
    const int n = blk * 4 + w;
    const int base = offs[n], end = offs[n + 1];
    const uint2* xw2 = (const uint2*)xfh;

    float a0, a1, a2, a3;
    {
        uint2 sp = xw2[(long)n * 32 + ql];
        float m = (half == 0) ? EPS1 : 0.f;
        a0 = m * us2f(sp.x); a1 = m * us2f(sp.x >> 16);
        a2 = m * us2f(sp.y); a3 = m * us2f(sp.y >> 16);
    }

    for (int i = base; i < end; i += 64) {
        int cnt = min(64, end - i);
        int e = (i + lane < end) ? elist[i + lane] : 0;
        int j = 0;
        for (; j + 16 <= cnt; j += 16) {       // 8 wave-loads = 16 edge rows
            uint2 p[8];
            #pragma unroll
            for (int q = 0; q < 8; q++) {
                int sj = __shfl(e, j + 2 * q + half);
                p[q] = xw2[(long)sj * 32 + ql];
            }
            #pragma unroll
            for (int q = 0; q < 8; q++) {
                a0 += us2f(p[q].x); a1 += us2f(p[q].x >> 16);
                a2 += us2f(p[q].y); a3 += us2f(p[q].y >> 16);
            }
        }
        for (; j + 2 <= cnt; j += 2) {
            int sj = __shfl(e, j + half);
            uint2 p = xw2[(long)sj * 32 + ql];
            a0 += us2f(p.x); a1 += us2f(p.x >> 16);
            a2 += us2f(p.y); a3 += us2f(p.y >> 16);
        }
        if (j < cnt && half == 0) {            // odd tail: half 0 only
            int sj = __shfl(e, j);
            uint2 p = xw2[(long)sj * 32 + ql];
            a0 += us2f(p.x); a1 += us2f(p.x >> 16);
            a2 += us2f(p.y); a3 += us2f(p.y >> 16);
        }
    }
    // combine the two halves (each lane pair ql, ql+32 holds same cols)
    a0 += __shfl_xor(a0, 32); a1 += __shfl_xor(a1, 32);
    a2 += __shfl_xor(a2, 32); a3 += __shfl_xor(a3, 32);

    if (csB) {
        int c = ql * 4;
        float fac = (float)(end - base) + EPS1;
        #pragma unroll
        for (int k = 0; k < 4; k++) {
            float mu = csB[c + k] * (1.f / NN);
            float var = csB[128 + c + k] * (1.f / NN) - mu * mu;
            float sc = b2f(g2[c + k]) * rsqrtf(var + BN_EPS);
            float sh = b2f(be2[c + k]) - mu * sc;
            float* ap = (k == 0) ? &a0 : (k == 1) ? &a1 : (k == 2) ? &a2 : &a3;
            *ap = sc * (*ap) + fac * sh;
        }
    }
    if (half == 0)
        ((uint2*)aggh)[(long)n * 32 + ql] = make_uint2(pack2(a0, a1), pack2(a2, a3));
}

// standalone pool for the last layer
__launch_bounds__(256)
__global__ void k_pool(const bf16* __restrict__ xfh, const int* __restrict__ boffs,
                       const float* __restrict__ csB, const bf16* __restrict__ g2,
                       const bf16* __restrict__ be2, float* __restrict__ feats_blk) {
    pool_body(blockIdx.x, threadIdx.x, xfh, boffs, csB, g2, be2, feats_blk);
}

// ---- MFMA GEMM: 512 threads, 128 rows/block (391 blocks) ----
#define WS_S 136
__launch_bounds__(512)
__global__ void k_gemm_mfma(const bf16* __restrict__ A, const bf16* __restrict__ WT,
                            const bf16* __restrict__ bias,
                            const float* __restrict__ bn_cs, const bf16* __restrict__ bn_g,
                            const bf16* __restrict__ bn_be,
                            bf16* __restrict__ Out, float* __restrict__ cs_out,
                            float* cs_zero) {
    __shared__ short Ws[128 * WS_S];   // 34816 B (reused as C-staging)
    __shared__ float s_cs[256];
    __shared__ float s_sc[DD], s_sh[DD];
    const int t = threadIdx.x;
    const int row0 = blockIdx.x * 128;

    if (t < 256) {
        if (cs_zero && blockIdx.x == 0) cs_zero[t] = 0.f;
        s_cs[t] = 0.f;
    }
    if (bn_cs && t < DD) {
        float mu = bn_cs[t] * (1.f / NN);
        float var = bn_cs[128 + t] * (1.f / NN) - mu * mu;
        float sc = b2f(bn_g[t]) * rsqrtf(var + BN_EPS);
        s_sc[t] = sc;
        s_sh[t] = b2f(bn_be[t]) - mu * sc;
    }
    {   // stage WT (2048 uint4, 4 iters x 512 thr)
        const uint4* Wg = (const uint4*)WT;
        #pragma unroll
        for (int i = 0; i < 4; i++) {
            int idx = i * 512 + t;
            int row = idx >> 4, seg = idx & 15;
            *(uint4*)(&Ws[row * WS_S + seg * 8]) = Wg[idx];
        }
    }
    __syncthreads();

    const int w = t >> 6;          // wave 0..7 -> rows w*16..+15
    const int lane = t & 63;
    const int m = lane & 15;
    const int half = lane >> 4;
    const int r = row0 + w * 16 + m;

    short8 afrag[4];
    if (r < NN) {
        #pragma unroll
        for (int kk = 0; kk < 4; kk++)
            afrag[kk] = *(const short8*)(A + (long)r * DD + kk * 32 + half * 8);
        if (bn_cs) {
            #pragma unroll
            for (int kk = 0; kk < 4; kk++) {
                int c0 = kk * 32 + half * 8;
                uint4 p = *(uint4*)&afrag[kk];
                float v0 = us2f(p.x) * s_sc[c0+0] + s_sh[c0+0];
                float v1 = us2f(p.x >> 16) * s_sc[c0+1] + s_sh[c0+1];
                float v2 = us2f(p.y) * s_sc[c0+2] + s_sh[c0+2];
                float v3 = us2f(p.y >> 16) * s_sc[c0+3] + s_sh[c0+3];
                float v4 = us2f(p.z) * s_sc[c0+4] + s_sh[c0+4];
                float v5 = us2f(p.z >> 16) * s_sc[c0+5] + s_sh[c0+5];
                float v6 = us2f(p.w) * s_sc[c0+6] + s_sh[c0+6];
                float v7 = us2f(p.w >> 16) * s_sc[c0+7] + s_sh[c0+7];
                p.x = pack2(v0, v1); p.y = pack2(v2, v3);
                p.z = pack2(v4, v5); p.w = pack2(v6, v7);
                afrag[kk] = *(short8*)&p;
            }
        }
    } else {
        #pragma unroll
        for (int kk = 0; kk < 4; kk++) afrag[kk] = (short8){0,0,0,0,0,0,0,0};
    }

    f32x4 acc[8];
    #pragma unroll
    for (int nt = 0; nt < 8; nt++) acc[nt] = (f32x4){0.f, 0.f, 0.f, 0.f};

    #pragma unroll
    for (int nt = 0; nt < 8; nt++) {
        const short* wrow = &Ws[(nt * 16 + m) * WS_S + half * 8];
        #pragma unroll
        for (int kk = 0; kk < 4; kk++) {
            short8 b = *(const short8*)(wrow + kk * 32);
            acc[nt] = __builtin_amdgcn_mfma_f32_16x16x32_bf16(afrag[kk], b, acc[nt], 0, 0, 0);
        }
    }

    __syncthreads();               // all waves done reading Ws -> reuse as Cs
    short* Cs = Ws;
    #pragma unroll
    for (int nt = 0; nt < 8; nt++) {
        int col = nt * 16 + m;
        float bi = b2f(bias[col]);
        float ps = 0.f, pq = 0.f;
        #pragma unroll
        for (int reg = 0; reg < 4; reg++) {
            int rr = row0 + w * 16 + half * 4 + reg;
            float o = fmaxf(acc[nt][reg] + bi, 0.f);
            Cs[(w * 16 + half * 4 + reg) * WS_S + col] = f2bfs(o);
            if (rr < NN) { ps += o; pq += o * o; }
        }
        ps += __shfl_xor(ps, 16); ps += __shfl_xor(ps, 32);
        pq += __shfl_xor(pq, 16); pq += __shfl_xor(pq, 32);
        if (half == 0) {
            atomicAdd(&s_cs[col], ps);
            atomicAdd(&s_cs[128 + col], pq);
        }
    }
    __syncthreads();
    // vectorized store of the 128x128 tile
    #pragma unroll
    for (int i = 0; i < 4; i++) {
        int idx = i * 512 + t;
        int row = idx >> 4, seg = idx & 15;
        int rr = row0 + row;
        if (rr < NN)
            *(uint4*)(Out + (long)rr * DD + seg * 8) = *(uint4*)(&Cs[row * WS_S + seg * 8]);
    }
    if (t < 256) atomicAdd(&cs_out[t], s_cs[t]);
}

// parallel feature stats: 20 blocks x 256 thr (32 cols x 8 g-groups)
__launch_bounds__(256)
__global__ void k_feat_stats(const float* __restrict__ feats, const bf16* __restrict__ bn_g,
                             const bf16* __restrict__ bn_b, float* __restrict__ sc6,
                             float* __restrict__ sh6) {
    __shared__ float rs[8][32], rq[8][32];
    const int j0 = blockIdx.x * 32;
    const int jl = threadIdx.x & 31, gg = threadIdx.x >> 5;
    float s = 0.f, q = 0.f;
    for (int g = gg; g < NG; g += 8) {
        float v = feats[(long)g * (NB * DD) + j0 + jl];
        s += v; q += v * v;
    }
    rs[gg][jl] = s; rq[gg][jl] = q;
    __syncthreads();
    if (gg == 0) {
        #pragma unroll
        for (int k = 1; k < 8; k++) { s += rs[k][jl]; q += rq[k][jl]; }
        int j = j0 + jl;
        float mu = s / NG;
        float var = q / NG - mu * mu;
        float sc = b2f(bn_g[j]) * rsqrtf(var + BN_EPS);
        sc6[j] = sc;
        sh6[j] = b2f(bn_b[j]) - mu * sc;
    }
}

__launch_bounds__(128)
__global__ void k_head(const int* __restrict__ flags, const float* __restrict__ feats,
                       const float* __restrict__ sc6, const float* __restrict__ sh6,
                       const bf16* __restrict__ Wc1T, const bf16* __restrict__ bc1,
                       const bf16* __restrict__ Wc2, const bf16* __restrict__ bc2,
                       void* out) {
    __shared__ float fs[NB * DD];
    __shared__ float f1[DD];
    __shared__ float lg[NC + 2];
    const int g = blockIdx.x, t = threadIdx.x;
    for (int j = t; j < NB * DD; j += 128)
        fs[j] = feats[(long)g * (NB * DD) + j] * sc6[j] + sh6[j];
    __syncthreads();
    float acc = b2f(bc1[t]);
    {   // Wc1T row t: 640 contiguous bf16 = 80 x short8
        const short8* wr = (const short8*)(Wc1T + (long)t * (NB * DD));
        #pragma unroll 4
        for (int jb = 0; jb < 80; jb++) {
            short8 wv = wr[jb];
            uint4 p = *(uint4*)&wv;
            float4 f0 = *(const float4*)&fs[jb * 8];
            float4 f1v = *(const float4*)&fs[jb * 8 + 4];
            acc += f0.x * us2f(p.x) + f0.y * us2f(p.x >> 16)
                 + f0.z * us2f(p.y) + f0.w * us2f(p.y >> 16)
                 + f1v.x * us2f(p.z) + f1v.y * us2f(p.z >> 16)
                 + f1v.z * us2f(p.w) + f1v.w * us2f(p.w >> 16);
        }
    }
    f1[t] = fmaxf(acc, 0.f);
    __syncthreads();
    if (t < NC) {
        float a = b2f(bc2[t]);
        for (int k = 0; k < DD; k++) a += f1[k] * b2f(Wc2[k * NC + t]);
        lg[t] = a;
    }
    __syncthreads();
    if (t == 0) {
        float m = -1e30f;
        for (int c = 0; c < NC; c++) m = fmaxf(m, lg[c]);
        float s = 0.f;
        for (int c = 0; c < NC; c++) s += expf(lg[c] - m);
        lg[NC] = m + logf(s);
    }
    __syncthreads();
    if (t < NC) {
        float val = lg[t] - lg[NC];
        if (flags[0]) ((bf16*)out)[g * NC + t] = __float2bfloat16(val);
        else          ((float*)out)[g * NC + t] = val;
    }
}

extern "C" void kernel_launch(void* const* d_in, const int* in_sizes, int n_in,
                              void* d_out, int out_size, void* d_ws, size_t ws_size,
                              hipStream_t stream) {
    const void* x     = d_in[0];
    const int*  ei    = (const int*)d_in[1];
    const int*  batch = (const int*)d_in[2];

    float* ws    = (float*)d_ws;
    bf16*  aggh  = (bf16*)(ws + OFF_AGGH);
    bf16*  xfh   = (bf16*)(ws + OFF_XF);
    bf16*  h1h   = (bf16*)(ws + OFF_H1);
    float* feats = ws + OFF_FEATS;
    float* csA   = ws + OFF_CSA;
    float* csB   = ws + OFF_CSB;
    float* sc6   = ws + OFF_SC6;
    float* sh6   = ws + OFF_SH6;
    int*   flags = (int*)(ws + OFF_FLAGS);
    bf16*  pb    = (bf16*)(ws + OFF_PARAMS);
    int*   deg   = (int*)(ws + OFF_DEG);
    int*   offs  = (int*)(ws + OFF_OFFS);
    int*   elist = (int*)(ws + OFF_ELIST);
    int*   bdeg  = (int*)(ws + OFF_BDEG);
    int*   boffs = (int*)(ws + OFF_BOFFS);
    int*   rank  = (int*)(ws + OFF_RANK);
    int*   part  = (int*)(ws + OFF_PART);
    int*   erank = (int*)(ws + OFF_ERANK);

    bf16 *pW1T = pb + P_W1T, *pW2T = pb + P_W2T, *pWc1 = pb + P_WC1;
    bf16 *pb1 = pb + P_B1, *pg1 = pb + P_G1, *pbe1 = pb + P_BE1;
    bf16 *pb2 = pb + P_B2, *pg2 = pb + P_G2, *pbe2 = pb + P_BE2;
    bf16 *pbng = pb + P_BNG, *pbnb = pb + P_BNB;
    bf16 *pbc1 = pb + P_BC1, *pWc2 = pb + P_WC2, *pbc2 = pb + P_BC2;

    k_detect<<<1, 256, 0, stream>>>((const unsigned*)x, ei, batch, flags, bdeg);

    k_bhist<<<(NN + 255) / 256, 256, 0, stream>>>(flags, batch, bdeg, deg);
    k_bscan<<<1, 512, 0, stream>>>(bdeg, boffs);
    k_bplace<<<(NN + 255) / 256, 256, 0, stream>>>(flags, batch, bdeg, rank);

    SmallSrc ss;
    ss.s[0] = d_in[4];  ss.s[1] = d_in[5];  ss.s[2] = d_in[6];
    ss.s[3] = d_in[8];  ss.s[4] = d_in[9];  ss.s[5] = d_in[10];
    ss.s[6] = d_in[11]; ss.s[7] = d_in[12];
    ss.s[8] = d_in[14]; ss.s[9] = d_in[15]; ss.s[10] = d_in[16];
    k_convert_all<<<CVX_BLOCKS + CVP_BLOCKS, 256, 0, stream>>>(
        flags, x, rank, xfh, d_in[3], d_in[7], d_in[13], ss, pb);

    k_hist<<<NE / 256, 256, 0, stream>>>(flags, ei, rank, deg, erank);
    k_scan_part<<<49, 256, 0, stream>>>(deg, part);
    k_scan_apply<<<49, 256, 0, stream>>>(deg, part, offs);
    k_place<<<NE / 256, 256, 0, stream>>>(flags, ei, rank, offs, erank, elist);

    const int gemm_blocks = (NN + 127) / 128;   // 391
    for (int i = 0; i < NB; i++) {
        // gather(i) + pool(i-1) in one launch
        k_gather_pool<<<GATHER_BLOCKS + NG, 256, 0, stream>>>(
            offs, elist, xfh, aggh,
            (i == 0) ? nullptr : csB,
            pg2 + (i - 1) * DD, pbe2 + (i - 1) * DD, csA,
            boffs, (i == 0) ? nullptr : feats + (i - 1) * DD);
        // GEMM1: aggh -> h1h, stats -> csA, zero csB
        k_gemm_mfma<<<gemm_blocks, 512, 0, stream>>>(aggh, pW1T + i * DD * DD, pb1 + i * DD,
                                                     nullptr, nullptr, nullptr,
                                                     h1h, csA, csB);
        // GEMM2: bn1(h1h) -> xfh, stats -> csB
        k_gemm_mfma<<<gemm_blocks, 512, 0, stream>>>(h1h, pW2T + i * DD * DD, pb2 + i * DD,
                                                     csA, pg1 + i * DD, pbe1 + i * DD,
                                                     xfh, csB, nullptr);
    }
    // final layer pool
    k_pool<<<NG, 256, 0, stream>>>(xfh, boffs, csB, pg2 + (NB - 1) * DD,
                                   pbe2 + (NB - 1) * DD, feats + (NB - 1) * DD);

    k_feat_stats<<<20, 256, 0, stream>>>(feats, pbng, pbnb, sc6, sh6);
    k_head<<<NG, 128, 0, stream>>>(flags, feats, sc6, sh6, pWc1, pbc1, pWc2, pbc2, d_out);
}

// Round 9
// 632.682 us; speedup vs baseline: 1.0891x; 1.0215x over previous
//
#include <hip/hip_runtime.h>
#include <hip/hip_bf16.h>

#define NN 50000      // nodes
#define NE 800000     // edges
#define DD 128        // hidden dim
#define NB 5          // GIN blocks
#define NG 512        // graphs
#define NC 10         // classes
#define BN_EPS 1e-5f
#define EPS1 129.0f   // 1 + eps_gin
#define GATHER_BLOCKS 12500   // NN/4
#define NXCD 8

typedef __hip_bfloat16 bf16;
typedef __attribute__((ext_vector_type(8))) short short8;
typedef __attribute__((ext_vector_type(4))) float f32x4;

__device__ __forceinline__ float b2f(const bf16 v) { return __bfloat162float(v); }
__device__ __forceinline__ float us2f(unsigned int s) {
    return __uint_as_float((s & 0xffffu) << 16);
}
__device__ __forceinline__ unsigned pack2(float a, float b) {
    union { bf16 h; unsigned short u; } ua, ub;
    ua.h = __float2bfloat16(a); ub.h = __float2bfloat16(b);
    return ((unsigned)ub.u << 16) | (unsigned)ua.u;
}
__device__ __forceinline__ short f2bfs(float f) {
    union { bf16 h; short s; } u; u.h = __float2bfloat16(f); return u.s;
}

// ---- workspace layout (float offsets) ----
#define OFF_AGGH   0            // bf16 [NN,128]
#define OFF_XF     3200000      // bf16 [NN,128]
#define OFF_H1     6400000      // bf16 [NN,128]
#define OFF_FEATS  9600000      // fp32 512*640
#define OFF_CSA    9927680      // 256: sum[0:128), sumsq[128:256)
#define OFF_CSB    9927936      // 256
#define OFF_SC6    9928192      // 640
#define OFF_SH6    9928832      // 640
#define OFF_FLAGS  9929472      // 8 ints
#define OFF_PARAMS 9929480      // bf16 region
#define OFF_DEG    10055680     // int 50000
#define OFF_OFFS   10105680     // int 50001
#define OFF_ELIST  10155712     // int 800000
#define OFF_BDEG   10955712     // int 512
#define OFF_BOFFS  10956224     // int 513
#define OFF_RANK   10956800     // int 50000
#define OFF_PART   11006800     // int 64
#define OFF_ERANK  11006864     // int 800000 (per-edge rank within dst segment)

// bf16 param region (bf16 element offsets)
#define P_W1T  0
#define P_W2T  81920
#define P_WC1  163840         // stored TRANSPOSED: [out_col 128][in_j 640]
#define P_B1   245760
#define P_G1   246400
#define P_BE1  247040
#define P_B2   247680
#define P_G2   248320
#define P_BE2  248960
#define P_BNG  249600
#define P_BNB  250240
#define P_BC1  250880
#define P_WC2  251008
#define P_BC2  252288

#define N_BIGPAR   245760
#define N_SMALLPAR 6538
#define CVX_BLOCKS 3125   // 800000/256 (x-convert portion)
#define CVP_BLOCKS ((N_BIGPAR + N_SMALLPAR + 255) / 256)   // = 986 (param portion)

struct SmallSrc { const void* s[11]; };

// ---- dtype detection (also zeroes bdeg: runs before k_bhist) ----
__global__ void k_detect(const unsigned* __restrict__ xw, const int* __restrict__ eiw,
                         const int* __restrict__ bw, int* flags, int* __restrict__ bdeg) {
    __shared__ int sh[3];
    const int t = threadIdx.x;  // 256
    bdeg[t] = 0; bdeg[256 + t] = 0;
    if (t < 3) sh[t] = 0;
    __syncthreads();
    int c = 0;
    for (int i = 0; i < 16; i++) {
        unsigned w = xw[t * 16 + i];
        unsigned e = (w >> 7) & 0xff;
        c += (e >= 110 && e <= 131) ? 1 : 0;
    }
    atomicAdd(&sh[0], c);
    atomicAdd(&sh[1], (eiw[2 * t + 1] != 0) ? 1 : 0);
    atomicAdd(&sh[2], (bw[2 * t + 1] != 0) ? 1 : 0);
    __syncthreads();
    if (t == 0) {
        flags[0] = (sh[0] > 2048) ? 1 : 0;
        flags[1] = (sh[1] < 8) ? 1 : 0;
        flags[2] = (sh[2] < 8) ? 1 : 0;
    }
}

// ---- batch CSR; also zeroes deg (runs before k_hist) ----
__global__ void k_bhist(const int* __restrict__ flags, const int* __restrict__ batch,
                        int* __restrict__ bdeg, int* __restrict__ deg) {
    int n = blockIdx.x * 256 + threadIdx.x;
    if (n >= NN) return;
    deg[n] = 0;
    int g = flags[2] ? batch[2 * n] : batch[n];
    atomicAdd(&bdeg[g], 1);
}

__launch_bounds__(512)
__global__ void k_bscan(int* __restrict__ bdeg, int* __restrict__ boffs) {
    __shared__ int part[512];
    const int t = threadIdx.x;
    int d0 = bdeg[t];
    part[t] = d0;
    __syncthreads();
    for (int d = 1; d < 512; d <<= 1) {
        int v = (t >= d) ? part[t - d] : 0;
        __syncthreads();
        part[t] += v;
        __syncthreads();
    }
    int ex = part[t] - d0;
    boffs[t] = ex;
    bdeg[t] = ex;   // cursor
    if (t == 511) boffs[512] = part[511];
}

// rank[n] = permuted (graph-contiguous) id of old node n
__global__ void k_bplace(const int* __restrict__ flags, const int* __restrict__ batch,
                         int* __restrict__ bcur, int* __restrict__ rank) {
    int n = blockIdx.x * 256 + threadIdx.x;
    if (n >= NN) return;
    int g = flags[2] ? batch[2 * n] : batch[n];
    rank[n] = atomicAdd(&bcur[g], 1);
}

// merged: x -> bf16 xfh (permuted rows)  +  all param conversion
__global__ void k_convert_all(const int* __restrict__ flags, const void* __restrict__ xr,
                              const int* __restrict__ rank, bf16* __restrict__ xfh,
                              const void* w1, const void* w2, const void* wc1,
                              SmallSrc srcs, bf16* __restrict__ pb) {
    if (blockIdx.x < CVX_BLOCKS) {
        int i = blockIdx.x * 256 + threadIdx.x;   // NN*DD/8 = 800000 chunks
        int r = i >> 4, seg = i & 15;
        uint4 o;
        if (flags[0]) {
            o = ((const uint4*)xr)[i];
        } else {
            float4 a = ((const float4*)xr)[2 * i], b = ((const float4*)xr)[2 * i + 1];
            o.x = pack2(a.x, a.y); o.y = pack2(a.z, a.w);
            o.z = pack2(b.x, b.y); o.w = pack2(b.z, b.w);
        }
        ((uint4*)xfh)[(long)rank[r] * 16 + seg] = o;
        return;
    }
    int i = (blockIdx.x - CVX_BLOCKS) * 256 + threadIdx.x;
    if (i < N_BIGPAR) {
        int which = i / 81920, j = i % 81920;
        const void* src = (which == 0) ? w1 : (which == 1) ? w2 : wc1;
        float v = flags[0] ? us2f(((const unsigned short*)src)[j]) : ((const float*)src)[j];
        if (which == 2) {
            int rowj = j >> 7, col = j & 127;      // Wc1 is [640][128]
            pb[P_WC1 + col * (NB * DD) + rowj] = __float2bfloat16(v);
        } else {
            int layer = j >> 14, rem = j & 16383;
            int k = rem >> 7, c = rem & 127;
            bf16* dst = pb + (which == 0 ? P_W1T : P_W2T);
            dst[(layer << 14) + c * DD + k] = __float2bfloat16(v);
        }
    } else {
        int j = i - N_BIGPAR;
        if (j >= N_SMALLPAR) return;
        int seg, off;
        if (j < 5120)      { seg = j / 640; off = j - seg * 640; }
        else if (j < 5248) { seg = 8;  off = j - 5120; }
        else if (j < 6528) { seg = 9;  off = j - 5248; }
        else               { seg = 10; off = j - 6528; }
        const void* s = srcs.s[seg];
        float v = flags[0] ? us2f(((const unsigned short*)s)[off]) : ((const float*)s)[off];
        pb[P_B1 + j] = __float2bfloat16(v);
    }
}

// ---- edge CSR (permuted domain) ----
__global__ void k_hist(const int* __restrict__ flags, const int* __restrict__ ei,
                       const int* __restrict__ rank, int* __restrict__ deg,
                       int* __restrict__ erank) {
    int e = blockIdx.x * 256 + threadIdx.x;   // NE
    int d = flags[1] ? ((const int2*)ei)[NE + e].x : ei[NE + e];
    erank[e] = atomicAdd(&deg[rank[d]], 1);
}

__global__ void k_scan_part(const int* __restrict__ deg, int* __restrict__ part) {
    __shared__ int red[256];
    const int b = blockIdx.x, t = threadIdx.x;   // 49 x 256
    int i0 = b * 1024 + t * 4;
    int s = 0;
    if (i0 + 3 < NN) {
        int4 v = *(const int4*)(deg + i0);
        s = v.x + v.y + v.z + v.w;
    } else {
        for (int k = 0; k < 4; k++) if (i0 + k < NN) s += deg[i0 + k];
    }
    red[t] = s;
    __syncthreads();
    for (int d = 128; d > 0; d >>= 1) {
        if (t < d) red[t] += red[t + d];
        __syncthreads();
    }
    if (t == 0) part[b] = red[0];
}

__global__ void k_scan_apply(const int* __restrict__ deg, const int* __restrict__ part,
                             int* __restrict__ offs) {
    __shared__ int red[256];
    __shared__ int base_sh, total_sh;
    const int b = blockIdx.x, t = threadIdx.x;   // 49 x 256
    if (t < 64) {
        int v = (t < 49) ? part[t] : 0;
        int s = v;
        for (int d = 1; d < 64; d <<= 1) {
            int x = __shfl_up(s, d);
            if (t >= d) s += x;
        }
        if (t == b)  base_sh = s - v;
        if (t == 48) total_sh = s;
    }
    int i0 = b * 1024 + t * 4;
    int v[4]; int s = 0;
    #pragma unroll
    for (int k = 0; k < 4; k++) {
        int idx = i0 + k;
        v[k] = (idx < NN) ? deg[idx] : 0;
        s += v[k];
    }
    red[t] = s;
    __syncthreads();
    for (int d = 1; d < 256; d <<= 1) {
        int x = (t >= d) ? red[t - d] : 0;
        __syncthreads();
        red[t] += x;
        __syncthreads();
    }
    if (b == 0 && t == 0) offs[NN] = total_sh;
    int pre = base_sh + ((t == 0) ? 0 : red[t - 1]);
    #pragma unroll
    for (int k = 0; k < 4; k++) {
        int idx = i0 + k;
        if (idx < NN) { offs[idx] = pre; pre += v[k]; }
    }
}

// atomic-free placement: slot = offs[rank[d]] + erank[e]
__global__ void k_place(const int* __restrict__ flags, const int* __restrict__ ei,
                        const int* __restrict__ rank, const int* __restrict__ offs,
                        const int* __restrict__ erank, int* __restrict__ elist) {
    int e = blockIdx.x * 256 + threadIdx.x;   // NE
    int s, d;
    if (flags[1]) { s = ((const int2*)ei)[e].x; d = ((const int2*)ei)[NE + e].x; }
    else          { s = ei[e];                  d = ei[NE + e]; }
    elist[offs[rank[d]] + erank[e]] = rank[s];
}

// pool body: per-graph sum of bn(xfh rows) -> feats[g][blk*128..]
__device__ __forceinline__ void pool_body(int g, int t, const bf16* __restrict__ xfh,
                                          const int* __restrict__ boffs,
                                          const float* __restrict__ csB,
                                          const bf16* __restrict__ g2,
                                          const bf16* __restrict__ be2,
                                          float* __restrict__ feats_blk) {
    __shared__ float2 red[3][64];
    const int l = t & 63;    // col pair index
    const int h = t >> 6;    // 0..3 row split
    const int lo = boffs[g], hi = boffs[g + 1];
    const unsigned* xw = (const unsigned*)xfh;
    float s0 = 0.f, s1 = 0.f;
    for (int n = lo + h; n < hi; n += 4) {
        unsigned p = xw[(long)n * 64 + l];
        s0 += us2f(p); s1 += us2f(p >> 16);
    }
    if (h) red[h - 1][l] = make_float2(s0, s1);
    __syncthreads();
    if (h == 0) {
        s0 += red[0][l].x + red[1][l].x + red[2][l].x;
        s1 += red[0][l].y + red[1][l].y + red[2][l].y;
        int c = l * 2;
        float mu0 = csB[c] * (1.f / NN);
        float var0 = csB[128 + c] * (1.f / NN) - mu0 * mu0;
        float sc0 = b2f(g2[c]) * rsqrtf(var0 + BN_EPS);
        float sh0 = b2f(be2[c]) - mu0 * sc0;
        float mu1 = csB[c + 1] * (1.f / NN);
        float var1 = csB[128 + c + 1] * (1.f / NN) - mu1 * mu1;
        float sc1 = b2f(g2[c + 1]) * rsqrtf(var1 + BN_EPS);
        float sh1 = b2f(be2[c + 1]) - mu1 * sc1;
        float cnt = (float)(hi - lo);
        float* fp = feats_blk + (long)g * (NB * DD) + c;
        fp[0] = sc0 * s0 + cnt * sh0;
        fp[1] = sc1 * s1 + cnt * sh1;
    }
}

// combined: blocks [0,12500) gather layer i; blocks [12500,13012) pool layer i-1.
// Gather v5: same per-node accumulation ORDER as v2 (bit-identical results);
// unified group loop — up to 8 pair-loads issued per group before any consume,
// so the former serial pair-phase (load->consume x ~3.5 for 47% of nodes) now
// has all its L3 round-trips in flight at once.
__global__ void k_gather_pool(const int* __restrict__ offs, const int* __restrict__ elist,
                              const bf16* __restrict__ xfh, bf16* __restrict__ aggh,
                              const float* __restrict__ csB, const bf16* __restrict__ g2,
                              const bf16* __restrict__ be2, float* __restrict__ csA_zero,
                              const int* __restrict__ boffs, float* __restrict__ feats_prev) {
    if (blockIdx.x >= GATHER_BLOCKS) {
        if (feats_prev)
            pool_body(blockIdx.x - GATHER_BLOCKS, threadIdx.x, xfh, boffs,
                      csB, g2, be2, feats_prev);
        return;
    }
    if (blockIdx.x == 0) csA_zero[threadIdx.x] = 0.f;   // 256 floats
    // bijective XCD swizzle (GATHER_BLOCKS = 8*1562 + 4)
    int blk;
    {
        const int q = GATHER_BLOCKS / NXCD, r = GATHER_BLOCKS % NXCD;
        int xcd = blockIdx.x % NXCD, pos = blockIdx.x / NXCD;
        blk = (xcd < r) ? xcd * (q + 1) + pos : r * (q + 1) + (xcd - r) * q + pos;
    }
    const int w = threadIdx.x >> 6;
    const int lane = threadIdx.x & 63;
    const int half = lane >> 5;        // which of 2 concurrent edges
    const int ql = lane & 31;          // uint2 column chunk (4 bf16 cols)
    const int n = blk * 4 + w;
    const int base = offs[n], end = offs[n + 1];
    const uint2* xw2 = (const uint2*)xfh;

    float a0, a1, a2, a3;
    {
        uint2 sp = xw2[(long)n * 32 + ql];
        float m = (half == 0) ? EPS1 : 0.f;
        a0 = m * us2f(sp.x); a1 = m * us2f(sp.x >> 16);
        a2 = m * us2f(sp.y); a3 = m * us2f(sp.y >> 16);
    }

    for (int i = base; i < end; i += 64) {
        int cnt = min(64, end - i);
        int e = (i + lane < end) ? elist[i + lane] : 0;
        int j = 0;
        while (j < cnt) {
            int rem = cnt - j;
            if (rem >= 2) {
                int g = (rem >> 1) < 8 ? (rem >> 1) : 8;   // pair-loads this group
                uint2 p[8];
                #pragma unroll
                for (int q = 0; q < 8; q++) {
                    if (q < g) {
                        int sj = __shfl(e, j + 2 * q + half);
                        p[q] = xw2[(long)sj * 32 + ql];
                    }
                }
                #pragma unroll
                for (int q = 0; q < 8; q++) {
                    if (q < g) {
                        a0 += us2f(p[q].x); a1 += us2f(p[q].x >> 16);
                        a2 += us2f(p[q].y); a3 += us2f(p[q].y >> 16);
                    }
                }
                j += 2 * g;
            } else {                               // odd tail: half 0 only
                if (half == 0) {
                    int sj = __shfl(e, j);
                    uint2 p = xw2[(long)sj * 32 + ql];
                    a0 += us2f(p.x); a1 += us2f(p.x >> 16);
                    a2 += us2f(p.y); a3 += us2f(p.y >> 16);
                }
                j++;
            }
        }
    }
    // combine the two halves (each lane pair ql, ql+32 holds same cols)
    a0 += __shfl_xor(a0, 32); a1 += __shfl_xor(a1, 32);
    a2 += __shfl_xor(a2, 32); a3 += __shfl_xor(a3, 32);

    if (csB) {
        int c = ql * 4;
        float fac = (float)(end - base) + EPS1;
        #pragma unroll
        for (int k = 0; k < 4; k++) {
            float mu = csB[c + k] * (1.f / NN);
            float var = csB[128 + c + k] * (1.f / NN) - mu * mu;
            float sc = b2f(g2[c + k]) * rsqrtf(var + BN_EPS);
            float sh = b2f(be2[c + k]) - mu * sc;
            float* ap = (k == 0) ? &a0 : (k == 1) ? &a1 : (k == 2) ? &a2 : &a3;
            *ap = sc * (*ap) + fac * sh;
        }
    }
    if (half == 0)
        ((uint2*)aggh)[(long)n * 32 + ql] = make_uint2(pack2(a0, a1), pack2(a2, a3));
}

// standalone pool for the last layer
__launch_bounds__(256)
__global__ void k_pool(const bf16* __restrict__ xfh, const int* __restrict__ boffs,
                       const float* __restrict__ csB, const bf16* __restrict__ g2,
                       const bf16* __restrict__ be2, float* __restrict__ feats_blk) {
    pool_body(blockIdx.x, threadIdx.x, xfh, boffs, csB, g2, be2, feats_blk);
}

// ---- MFMA GEMM: 512 threads, 128 rows/block (391 blocks) ----
#define WS_S 136
__launch_bounds__(512)
__global__ void k_gemm_mfma(const bf16* __restrict__ A, const bf16* __restrict__ WT,
                            const bf16* __restrict__ bias,
                            const float* __restrict__ bn_cs, const bf16* __restrict__ bn_g,
                            const bf16* __restrict__ bn_be,
                            bf16* __restrict__ Out, float* __restrict__ cs_out,
                            float* cs_zero) {
    __shared__ short Ws[128 * WS_S];   // 34816 B (reused as C-staging)
    __shared__ float s_cs[256];
    __shared__ float s_sc[DD], s_sh[DD];
    const int t = threadIdx.x;
    const int row0 = blockIdx.x * 128;

    if (t < 256) {
        if (cs_zero && blockIdx.x == 0) cs_zero[t] = 0.f;
        s_cs[t] = 0.f;
    }
    if (bn_cs && t < DD) {
        float mu = bn_cs[t] * (1.f / NN);
        float var = bn_cs[128 + t] * (1.f / NN) - mu * mu;
        float sc = b2f(bn_g[t]) * rsqrtf(var + BN_EPS);
        s_sc[t] = sc;
        s_sh[t] = b2f(bn_be[t]) - mu * sc;
    }
    {   // stage WT (2048 uint4, 4 iters x 512 thr)
        const uint4* Wg = (const uint4*)WT;
        #pragma unroll
        for (int i = 0; i < 4; i++) {
            int idx = i * 512 + t;
            int row = idx >> 4, seg = idx & 15;
            *(uint4*)(&Ws[row * WS_S + seg * 8]) = Wg[idx];
        }
    }
    __syncthreads();

    const int w = t >> 6;          // wave 0..7 -> rows w*16..+15
    const int lane = t & 63;
    const int m = lane & 15;
    const int half = lane >> 4;
    const int r = row0 + w * 16 + m;

    short8 afrag[4];
    if (r < NN) {
        #pragma unroll
        for (int kk = 0; kk < 4; kk++)
            afrag[kk] = *(const short8*)(A + (long)r * DD + kk * 32 + half * 8);
        if (bn_cs) {
            #pragma unroll
            for (int kk = 0; kk < 4; kk++) {
                int c0 = kk * 32 + half * 8;
                uint4 p = *(uint4*)&afrag[kk];
                float v0 = us2f(p.x) * s_sc[c0+0] + s_sh[c0+0];
                float v1 = us2f(p.x >> 16) * s_sc[c0+1] + s_sh[c0+1];
                float v2 = us2f(p.y) * s_sc[c0+2] + s_sh[c0+2];
                float v3 = us2f(p.y >> 16) * s_sc[c0+3] + s_sh[c0+3];
                float v4 = us2f(p.z) * s_sc[c0+4] + s_sh[c0+4];
                float v5 = us2f(p.z >> 16) * s_sc[c0+5] + s_sh[c0+5];
                float v6 = us2f(p.w) * s_sc[c0+6] + s_sh[c0+6];
                float v7 = us2f(p.w >> 16) * s_sc[c0+7] + s_sh[c0+7];
                p.x = pack2(v0, v1); p.y = pack2(v2, v3);
                p.z = pack2(v4, v5); p.w = pack2(v6, v7);
                afrag[kk] = *(short8*)&p;
            }
        }
    } else {
        #pragma unroll
        for (int kk = 0; kk < 4; kk++) afrag[kk] = (short8){0,0,0,0,0,0,0,0};
    }

    f32x4 acc[8];
    #pragma unroll
    for (int nt = 0; nt < 8; nt++) acc[nt] = (f32x4){0.f, 0.f, 0.f, 0.f};

    #pragma unroll
    for (int nt = 0; nt < 8; nt++) {
        const short* wrow = &Ws[(nt * 16 + m) * WS_S + half * 8];
        #pragma unroll
        for (int kk = 0; kk < 4; kk++) {
            short8 b = *(const short8*)(wrow + kk * 32);
            acc[nt] = __builtin_amdgcn_mfma_f32_16x16x32_bf16(afrag[kk], b, acc[nt], 0, 0, 0);
        }
    }

    __syncthreads();               // all waves done reading Ws -> reuse as Cs
    short* Cs = Ws;
    #pragma unroll
    for (int nt = 0; nt < 8; nt++) {
        int col = nt * 16 + m;
        float bi = b2f(bias[col]);
        float ps = 0.f, pq = 0.f;
        #pragma unroll
        for (int reg = 0; reg < 4; reg++) {
            int rr = row0 + w * 16 + half * 4 + reg;
            float o = fmaxf(acc[nt][reg] + bi, 0.f);
            Cs[(w * 16 + half * 4 + reg) * WS_S + col] = f2bfs(o);
            if (rr < NN) { ps += o; pq += o * o; }
        }
        ps += __shfl_xor(ps, 16); ps += __shfl_xor(ps, 32);
        pq += __shfl_xor(pq, 16); pq += __shfl_xor(pq, 32);
        if (half == 0) {
            atomicAdd(&s_cs[col], ps);
            atomicAdd(&s_cs[128 + col], pq);
        }
    }
    __syncthreads();
    // vectorized store of the 128x128 tile
    #pragma unroll
    for (int i = 0; i < 4; i++) {
        int idx = i * 512 + t;
        int row = idx >> 4, seg = idx & 15;
        int rr = row0 + row;
        if (rr < NN)
            *(uint4*)(Out + (long)rr * DD + seg * 8) = *(uint4*)(&Cs[row * WS_S + seg * 8]);
    }
    if (t < 256) atomicAdd(&cs_out[t], s_cs[t]);
}

// parallel feature stats: 20 blocks x 256 thr (32 cols x 8 g-groups)
__launch_bounds__(256)
__global__ void k_feat_stats(const float* __restrict__ feats, const bf16* __restrict__ bn_g,
                             const bf16* __restrict__ bn_b, float* __restrict__ sc6,
                             float* __restrict__ sh6) {
    __shared__ float rs[8][32], rq[8][32];
    const int j0 = blockIdx.x * 32;
    const int jl = threadIdx.x & 31, gg = threadIdx.x >> 5;
    float s = 0.f, q = 0.f;
    for (int g = gg; g < NG; g += 8) {
        float v = feats[(long)g * (NB * DD) + j0 + jl];
        s += v; q += v * v;
    }
    rs[gg][jl] = s; rq[gg][jl] = q;
    __syncthreads();
    if (gg == 0) {
        #pragma unroll
        for (int k = 1; k < 8; k++) { s += rs[k][jl]; q += rq[k][jl]; }
        int j = j0 + jl;
        float mu = s / NG;
        float var = q / NG - mu * mu;
        float sc = b2f(bn_g[j]) * rsqrtf(var + BN_EPS);
        sc6[j] = sc;
        sh6[j] = b2f(bn_b[j]) - mu * sc;
    }
}

__launch_bounds__(128)
__global__ void k_head(const int* __restrict__ flags, const float* __restrict__ feats,
                       const float* __restrict__ sc6, const float* __restrict__ sh6,
                       const bf16* __restrict__ Wc1T, const bf16* __restrict__ bc1,
                       const bf16* __restrict__ Wc2, const bf16* __restrict__ bc2,
                       void* out) {
    __shared__ float fs[NB * DD];
    __shared__ float f1[DD];
    __shared__ float lg[NC + 2];
    const int g = blockIdx.x, t = threadIdx.x;
    for (int j = t; j < NB * DD; j += 128)
        fs[j] = feats[(long)g * (NB * DD) + j] * sc6[j] + sh6[j];
    __syncthreads();
    float acc = b2f(bc1[t]);
    {   // Wc1T row t: 640 contiguous bf16 = 80 x short8
        const short8* wr = (const short8*)(Wc1T + (long)t * (NB * DD));
        #pragma unroll 4
        for (int jb = 0; jb < 80; jb++) {
            short8 wv = wr[jb];
            uint4 p = *(uint4*)&wv;
            float4 f0 = *(const float4*)&fs[jb * 8];
            float4 f1v = *(const float4*)&fs[jb * 8 + 4];
            acc += f0.x * us2f(p.x) + f0.y * us2f(p.x >> 16)
                 + f0.z * us2f(p.y) + f0.w * us2f(p.y >> 16)
                 + f1v.x * us2f(p.z) + f1v.y * us2f(p.z >> 16)
                 + f1v.z * us2f(p.w) + f1v.w * us2f(p.w >> 16);
        }
    }
    f1[t] = fmaxf(acc, 0.f);
    __syncthreads();
    if (t < NC) {
        float a = b2f(bc2[t]);
        for (int k = 0; k < DD; k++) a += f1[k] * b2f(Wc2[k * NC + t]);
        lg[t] = a;
    }
    __syncthreads();
    if (t == 0) {
        float m = -1e30f;
        for (int c = 0; c < NC; c++) m = fmaxf(m, lg[c]);
        float s = 0.f;
        for (int c = 0; c < NC; c++) s += expf(lg[c] - m);
        lg[NC] = m + logf(s);
    }
    __syncthreads();
    if (t < NC) {
        float val = lg[t] - lg[NC];
        if (flags[0]) ((bf16*)out)[g * NC + t] = __float2bfloat16(val);
        else          ((float*)out)[g * NC + t] = val;
    }
}

extern "C" void kernel_launch(void* const* d_in, const int* in_sizes, int n_in,
                              void* d_out, int out_size, void* d_ws, size_t ws_size,
                              hipStream_t stream) {
    const void* x     = d_in[0];
    const int*  ei    = (const int*)d_in[1];
    const int*  batch = (const int*)d_in[2];

    float* ws    = (float*)d_ws;
    bf16*  aggh  = (bf16*)(ws + OFF_AGGH);
    bf16*  xfh   = (bf16*)(ws + OFF_XF);
    bf16*  h1h   = (bf16*)(ws + OFF_H1);
    float* feats = ws + OFF_FEATS;
    float* csA   = ws + OFF_CSA;
    float* csB   = ws + OFF_CSB;
    float* sc6   = ws + OFF_SC6;
    float* sh6   = ws + OFF_SH6;
    int*   flags = (int*)(ws + OFF_FLAGS);
    bf16*  pb    = (bf16*)(ws + OFF_PARAMS);
    int*   deg   = (int*)(ws + OFF_DEG);
    int*   offs  = (int*)(ws + OFF_OFFS);
    int*   elist = (int*)(ws + OFF_ELIST);
    int*   bdeg  = (int*)(ws + OFF_BDEG);
    int*   boffs = (int*)(ws + OFF_BOFFS);
    int*   rank  = (int*)(ws + OFF_RANK);
    int*   part  = (int*)(ws + OFF_PART);
    int*   erank = (int*)(ws + OFF_ERANK);

    bf16 *pW1T = pb + P_W1T, *pW2T = pb + P_W2T, *pWc1 = pb + P_WC1;
    bf16 *pb1 = pb + P_B1, *pg1 = pb + P_G1, *pbe1 = pb + P_BE1;
    bf16 *pb2 = pb + P_B2, *pg2 = pb + P_G2, *pbe2 = pb + P_BE2;
    bf16 *pbng = pb + P_BNG, *pbnb = pb + P_BNB;
    bf16 *pbc1 = pb + P_BC1, *pWc2 = pb + P_WC2, *pbc2 = pb + P_BC2;

    k_detect<<<1, 256, 0, stream>>>((const unsigned*)x, ei, batch, flags, bdeg);

    k_bhist<<<(NN + 255) / 256, 256, 0, stream>>>(flags, batch, bdeg, deg);
    k_bscan<<<1, 512, 0, stream>>>(bdeg, boffs);
    k_bplace<<<(NN + 255) / 256, 256, 0, stream>>>(flags, batch, bdeg, rank);

    SmallSrc ss;
    ss.s[0] = d_in[4];  ss.s[1] = d_in[5];  ss.s[2] = d_in[6];
    ss.s[3] = d_in[8];  ss.s[4] = d_in[9];  ss.s[5] = d_in[10];
    ss.s[6] = d_in[11]; ss.s[7] = d_in[12];
    ss.s[8] = d_in[14]; ss.s[9] = d_in[15]; ss.s[10] = d_in[16];
    k_convert_all<<<CVX_BLOCKS + CVP_BLOCKS, 256, 0, stream>>>(
        flags, x, rank, xfh, d_in[3], d_in[7], d_in[13], ss, pb);

    k_hist<<<NE / 256, 256, 0, stream>>>(flags, ei, rank, deg, erank);
    k_scan_part<<<49, 256, 0, stream>>>(deg, part);
    k_scan_apply<<<49, 256, 0, stream>>>(deg, part, offs);
    k_place<<<NE / 256, 256, 0, stream>>>(flags, ei, rank, offs, erank, elist);

    const int gemm_blocks = (NN + 127) / 128;   // 391
    for (int i = 0; i < NB; i++) {
        // gather(i) + pool(i-1) in one launch
        k_gather_pool<<<GATHER_BLOCKS + NG, 256, 0, stream>>>(
            offs, elist, xfh, aggh,
            (i == 0) ? nullptr : csB,
            pg2 + (i - 1) * DD, pbe2 + (i - 1) * DD, csA,
            boffs, (i == 0) ? nullptr : feats + (i - 1) * DD);
        // GEMM1: aggh -> h1h, stats -> csA, zero csB
        k_gemm_mfma<<<gemm_blocks, 512, 0, stream>>>(aggh, pW1T + i * DD * DD, pb1 + i * DD,
                                                     nullptr, nullptr, nullptr,
                                                     h1h, csA, csB);
        // GEMM2: bn1(h1h) -> xfh, stats -> csB
        k_gemm_mfma<<<gemm_blocks, 512, 0, stream>>>(h1h, pW2T + i * DD * DD, pb2 + i * DD,
                                                     csA, pg1 + i * DD, pbe1 + i * DD,
                                                     xfh, csB, nullptr);
    }
    // final layer pool
    k_pool<<<NG, 256, 0, stream>>>(xfh, boffs, csB, pg2 + (NB - 1) * DD,
                                   pbe2 + (NB - 1) * DD, feats + (NB - 1) * DD);

    k_feat_stats<<<20, 256, 0, stream>>>(feats, pbng, pbnb, sc6, sh6);
    k_head<<<NG, 128, 0, stream>>>(flags, feats, sc6, sh6, pWc1, pbc1, pWc2, pbc2, d_out);
}

// Round 10
// 623.326 us; speedup vs baseline: 1.1054x; 1.0150x over previous
//
#include <hip/hip_runtime.h>
#include <hip/hip_bf16.h>

#define NN 50000      // nodes
#define NE 800000     // edges
#define DD 128        // hidden dim
#define NB 5          // GIN blocks
#define NG 512        // graphs
#define NC 10         // classes
#define BN_EPS 1e-5f
#define EPS1 129.0f   // 1 + eps_gin
#define GB2 6250      // gather blocks (8 nodes/block, 2 nodes/wave)
#define NXCD 8

typedef __hip_bfloat16 bf16;
typedef __attribute__((ext_vector_type(8))) short short8;
typedef __attribute__((ext_vector_type(4))) float f32x4;

__device__ __forceinline__ float b2f(const bf16 v) { return __bfloat162float(v); }
__device__ __forceinline__ float us2f(unsigned int s) {
    return __uint_as_float((s & 0xffffu) << 16);
}
__device__ __forceinline__ unsigned pack2(float a, float b) {
    union { bf16 h; unsigned short u; } ua, ub;
    ua.h = __float2bfloat16(a); ub.h = __float2bfloat16(b);
    return ((unsigned)ub.u << 16) | (unsigned)ua.u;
}
__device__ __forceinline__ short f2bfs(float f) {
    union { bf16 h; short s; } u; u.h = __float2bfloat16(f); return u.s;
}

// ---- workspace layout (float offsets) ----
#define OFF_AGGH   0            // bf16 [NN,128]
#define OFF_XF     3200000      // bf16 [NN,128]
#define OFF_H1     6400000      // bf16 [NN,128]
#define OFF_FEATS  9600000      // fp32 512*640
#define OFF_CSA    9927680      // 256: sum[0:128), sumsq[128:256)
#define OFF_CSB    9927936      // 256
#define OFF_SC6    9928192      // 640
#define OFF_SH6    9928832      // 640
#define OFF_FLAGS  9929472      // 8 ints
#define OFF_PARAMS 9929480      // bf16 region
#define OFF_DEG    10055680     // int 50000
#define OFF_OFFS   10105680     // int 50001
#define OFF_ELIST  10155712     // int 800000
#define OFF_BDEG   10955712     // int 512
#define OFF_BOFFS  10956224     // int 513
#define OFF_RANK   10956800     // int 50000
#define OFF_PART   11006800     // int 64
#define OFF_ERANK  11006864     // int 800000 (per-edge rank within dst segment)

// bf16 param region (bf16 element offsets)
#define P_W1T  0
#define P_W2T  81920
#define P_WC1  163840         // stored TRANSPOSED: [out_col 128][in_j 640]
#define P_B1   245760
#define P_G1   246400
#define P_BE1  247040
#define P_B2   247680
#define P_G2   248320
#define P_BE2  248960
#define P_BNG  249600
#define P_BNB  250240
#define P_BC1  250880
#define P_WC2  251008
#define P_BC2  252288

#define N_BIGPAR   245760
#define N_SMALLPAR 6538
#define CVX_BLOCKS 3125   // 800000/256 (x-convert portion)
#define CVP_BLOCKS ((N_BIGPAR + N_SMALLPAR + 255) / 256)   // = 986 (param portion)

struct SmallSrc { const void* s[11]; };

// ---- dtype detection (also zeroes bdeg: runs before k_bhist) ----
__global__ void k_detect(const unsigned* __restrict__ xw, const int* __restrict__ eiw,
                         const int* __restrict__ bw, int* flags, int* __restrict__ bdeg) {
    __shared__ int sh[3];
    const int t = threadIdx.x;  // 256
    bdeg[t] = 0; bdeg[256 + t] = 0;
    if (t < 3) sh[t] = 0;
    __syncthreads();
    int c = 0;
    for (int i = 0; i < 16; i++) {
        unsigned w = xw[t * 16 + i];
        unsigned e = (w >> 7) & 0xff;
        c += (e >= 110 && e <= 131) ? 1 : 0;
    }
    atomicAdd(&sh[0], c);
    atomicAdd(&sh[1], (eiw[2 * t + 1] != 0) ? 1 : 0);
    atomicAdd(&sh[2], (bw[2 * t + 1] != 0) ? 1 : 0);
    __syncthreads();
    if (t == 0) {
        flags[0] = (sh[0] > 2048) ? 1 : 0;
        flags[1] = (sh[1] < 8) ? 1 : 0;
        flags[2] = (sh[2] < 8) ? 1 : 0;
    }
}

// ---- batch CSR; also zeroes deg (runs before k_hist) ----
__global__ void k_bhist(const int* __restrict__ flags, const int* __restrict__ batch,
                        int* __restrict__ bdeg, int* __restrict__ deg) {
    int n = blockIdx.x * 256 + threadIdx.x;
    if (n >= NN) return;
    deg[n] = 0;
    int g = flags[2] ? batch[2 * n] : batch[n];
    atomicAdd(&bdeg[g], 1);
}

__launch_bounds__(512)
__global__ void k_bscan(int* __restrict__ bdeg, int* __restrict__ boffs) {
    __shared__ int part[512];
    const int t = threadIdx.x;
    int d0 = bdeg[t];
    part[t] = d0;
    __syncthreads();
    for (int d = 1; d < 512; d <<= 1) {
        int v = (t >= d) ? part[t - d] : 0;
        __syncthreads();
        part[t] += v;
        __syncthreads();
    }
    int ex = part[t] - d0;
    boffs[t] = ex;
    bdeg[t] = ex;   // cursor
    if (t == 511) boffs[512] = part[511];
}

// rank[n] = permuted (graph-contiguous) id of old node n
__global__ void k_bplace(const int* __restrict__ flags, const int* __restrict__ batch,
                         int* __restrict__ bcur, int* __restrict__ rank) {
    int n = blockIdx.x * 256 + threadIdx.x;
    if (n >= NN) return;
    int g = flags[2] ? batch[2 * n] : batch[n];
    rank[n] = atomicAdd(&bcur[g], 1);
}

// merged: x -> bf16 xfh (permuted rows)  +  all param conversion
__global__ void k_convert_all(const int* __restrict__ flags, const void* __restrict__ xr,
                              const int* __restrict__ rank, bf16* __restrict__ xfh,
                              const void* w1, const void* w2, const void* wc1,
                              SmallSrc srcs, bf16* __restrict__ pb) {
    if (blockIdx.x < CVX_BLOCKS) {
        int i = blockIdx.x * 256 + threadIdx.x;   // NN*DD/8 = 800000 chunks
        int r = i >> 4, seg = i & 15;
        uint4 o;
        if (flags[0]) {
            o = ((const uint4*)xr)[i];
        } else {
            float4 a = ((const float4*)xr)[2 * i], b = ((const float4*)xr)[2 * i + 1];
            o.x = pack2(a.x, a.y); o.y = pack2(a.z, a.w);
            o.z = pack2(b.x, b.y); o.w = pack2(b.z, b.w);
        }
        ((uint4*)xfh)[(long)rank[r] * 16 + seg] = o;
        return;
    }
    int i = (blockIdx.x - CVX_BLOCKS) * 256 + threadIdx.x;
    if (i < N_BIGPAR) {
        int which = i / 81920, j = i % 81920;
        const void* src = (which == 0) ? w1 : (which == 1) ? w2 : wc1;
        float v = flags[0] ? us2f(((const unsigned short*)src)[j]) : ((const float*)src)[j];
        if (which == 2) {
            int rowj = j >> 7, col = j & 127;      // Wc1 is [640][128]
            pb[P_WC1 + col * (NB * DD) + rowj] = __float2bfloat16(v);
        } else {
            int layer = j >> 14, rem = j & 16383;
            int k = rem >> 7, c = rem & 127;
            bf16* dst = pb + (which == 0 ? P_W1T : P_W2T);
            dst[(layer << 14) + c * DD + k] = __float2bfloat16(v);
        }
    } else {
        int j = i - N_BIGPAR;
        if (j >= N_SMALLPAR) return;
        int seg, off;
        if (j < 5120)      { seg = j / 640; off = j - seg * 640; }
        else if (j < 5248) { seg = 8;  off = j - 5120; }
        else if (j < 6528) { seg = 9;  off = j - 5248; }
        else               { seg = 10; off = j - 6528; }
        const void* s = srcs.s[seg];
        float v = flags[0] ? us2f(((const unsigned short*)s)[off]) : ((const float*)s)[off];
        pb[P_B1 + j] = __float2bfloat16(v);
    }
}

// ---- edge CSR (permuted domain) ----
__global__ void k_hist(const int* __restrict__ flags, const int* __restrict__ ei,
                       const int* __restrict__ rank, int* __restrict__ deg,
                       int* __restrict__ erank) {
    int e = blockIdx.x * 256 + threadIdx.x;   // NE
    int d = flags[1] ? ((const int2*)ei)[NE + e].x : ei[NE + e];
    erank[e] = atomicAdd(&deg[rank[d]], 1);
}

__global__ void k_scan_part(const int* __restrict__ deg, int* __restrict__ part) {
    __shared__ int red[256];
    const int b = blockIdx.x, t = threadIdx.x;   // 49 x 256
    int i0 = b * 1024 + t * 4;
    int s = 0;
    if (i0 + 3 < NN) {
        int4 v = *(const int4*)(deg + i0);
        s = v.x + v.y + v.z + v.w;
    } else {
        for (int k = 0; k < 4; k++) if (i0 + k < NN) s += deg[i0 + k];
    }
    red[t] = s;
    __syncthreads();
    for (int d = 128; d > 0; d >>= 1) {
        if (t < d) red[t] += red[t + d];
        __syncthreads();
    }
    if (t == 0) part[b] = red[0];
}

__global__ void k_scan_apply(const int* __restrict__ deg, const int* __restrict__ part,
                             int* __restrict__ offs) {
    __shared__ int red[256];
    __shared__ int base_sh, total_sh;
    const int b = blockIdx.x, t = threadIdx.x;   // 49 x 256
    if (t < 64) {
        int v = (t < 49) ? part[t] : 0;
        int s = v;
        for (int d = 1; d < 64; d <<= 1) {
            int x = __shfl_up(s, d);
            if (t >= d) s += x;
        }
        if (t == b)  base_sh = s - v;
        if (t == 48) total_sh = s;
    }
    int i0 = b * 1024 + t * 4;
    int v[4]; int s = 0;
    #pragma unroll
    for (int k = 0; k < 4; k++) {
        int idx = i0 + k;
        v[k] = (idx < NN) ? deg[idx] : 0;
        s += v[k];
    }
    red[t] = s;
    __syncthreads();
    for (int d = 1; d < 256; d <<= 1) {
        int x = (t >= d) ? red[t - d] : 0;
        __syncthreads();
        red[t] += x;
        __syncthreads();
    }
    if (b == 0 && t == 0) offs[NN] = total_sh;
    int pre = base_sh + ((t == 0) ? 0 : red[t - 1]);
    #pragma unroll
    for (int k = 0; k < 4; k++) {
        int idx = i0 + k;
        if (idx < NN) { offs[idx] = pre; pre += v[k]; }
    }
}

// atomic-free placement: slot = offs[rank[d]] + erank[e]
__global__ void k_place(const int* __restrict__ flags, const int* __restrict__ ei,
                        const int* __restrict__ rank, const int* __restrict__ offs,
                        const int* __restrict__ erank, int* __restrict__ elist) {
    int e = blockIdx.x * 256 + threadIdx.x;   // NE
    int s, d;
    if (flags[1]) { s = ((const int2*)ei)[e].x; d = ((const int2*)ei)[NE + e].x; }
    else          { s = ei[e];                  d = ei[NE + e]; }
    elist[offs[rank[d]] + erank[e]] = rank[s];
}

// pool body: per-graph sum of bn(xfh rows) -> feats[g][blk*128..]
__device__ __forceinline__ void pool_body(int g, int t, const bf16* __restrict__ xfh,
                                          const int* __restrict__ boffs,
                                          const float* __restrict__ csB,
                                          const bf16* __restrict__ g2,
                                          const bf16* __restrict__ be2,
                                          float* __restrict__ feats_blk) {
    __shared__ float2 red[3][64];
    const int l = t & 63;    // col pair index
    const int h = t >> 6;    // 0..3 row split
    const int lo = boffs[g], hi = boffs[g + 1];
    const unsigned* xw = (const unsigned*)xfh;
    float s0 = 0.f, s1 = 0.f;
    for (int n = lo + h; n < hi; n += 4) {
        unsigned p = xw[(long)n * 64 + l];
        s0 += us2f(p); s1 += us2f(p >> 16);
    }
    if (h) red[h - 1][l] = make_float2(s0, s1);
    __syncthreads();
    if (h == 0) {
        s0 += red[0][l].x + red[1][l].x + red[2][l].x;
        s1 += red[0][l].y + red[1][l].y + red[2][l].y;
        int c = l * 2;
        float mu0 = csB[c] * (1.f / NN);
        float var0 = csB[128 + c] * (1.f / NN) - mu0 * mu0;
        float sc0 = b2f(g2[c]) * rsqrtf(var0 + BN_EPS);
        float sh0 = b2f(be2[c]) - mu0 * sc0;
        float mu1 = csB[c + 1] * (1.f / NN);
        float var1 = csB[128 + c + 1] * (1.f / NN) - mu1 * mu1;
        float sc1 = b2f(g2[c + 1]) * rsqrtf(var1 + BN_EPS);
        float sh1 = b2f(be2[c + 1]) - mu1 * sc1;
        float cnt = (float)(hi - lo);
        float* fp = feats_blk + (long)g * (NB * DD) + c;
        fp[0] = sc0 * s0 + cnt * sh0;
        fp[1] = sc1 * s1 + cnt * sh1;
    }
}

// group-load macro: issue up to 8 pair-loads for one node (no consume)
#define GLOAD(P, GG, E, J, REM) \
    if ((REM) >= 2) { \
        GG = (REM) >> 1; if (GG > 8) GG = 8; \
        _Pragma("unroll") \
        for (int q = 0; q < 8; q++) { \
            if (q < GG) { \
                int sj = __shfl((E), (J) + 2 * q + half); \
                P[q] = xw2[(long)sj * 32 + ql]; \
            } \
        } \
    }
// consume macro: matches v5 order exactly (groups then odd tail)
#define GCONSUME(P, GG, E, J, REM, A0, A1, A2, A3) \
    if ((REM) >= 2) { \
        _Pragma("unroll") \
        for (int q = 0; q < 8; q++) { \
            if (q < GG) { \
                A0 += us2f(P[q].x); A1 += us2f(P[q].x >> 16); \
                A2 += us2f(P[q].y); A3 += us2f(P[q].y >> 16); \
            } \
        } \
        J += 2 * GG; \
    } else if ((REM) == 1) { \
        if (half == 0) { \
            int sj = __shfl((E), (J)); \
            uint2 pp = xw2[(long)sj * 32 + ql]; \
            A0 += us2f(pp.x); A1 += us2f(pp.x >> 16); \
            A2 += us2f(pp.y); A3 += us2f(pp.y >> 16); \
        } \
        J += 1; \
    }

// combined: blocks [0,GB2) gather layer i (2 nodes/wave); [GB2,GB2+512) pool i-1.
// Gather v6: per-node accumulation order IDENTICAL to v5 (bit-exact results);
// two nodes per wave with interleaved load groups — doubles bytes in flight
// per wave to hide the serial offs->elist->rows chain (R9: latency-bound).
__global__ void k_gather_pool(const int* __restrict__ offs, const int* __restrict__ elist,
                              const bf16* __restrict__ xfh, bf16* __restrict__ aggh,
                              const float* __restrict__ csB, const bf16* __restrict__ g2,
                              const bf16* __restrict__ be2, float* __restrict__ csA_zero,
                              const int* __restrict__ boffs, float* __restrict__ feats_prev) {
    if (blockIdx.x >= GB2) {
        if (feats_prev)
            pool_body(blockIdx.x - GB2, threadIdx.x, xfh, boffs,
                      csB, g2, be2, feats_prev);
        return;
    }
    if (blockIdx.x == 0) csA_zero[threadIdx.x] = 0.f;   // 256 floats
    // bijective XCD swizzle (GB2 = 8*781 + 2)
    int blk;
    {
        const int q = GB2 / NXCD, r = GB2 % NXCD;
        int xcd = blockIdx.x % NXCD, pos = blockIdx.x / NXCD;
        blk = (xcd < r) ? xcd * (q + 1) + pos : r * (q + 1) + (xcd - r) * q + pos;
    }
    const int w = threadIdx.x >> 6;
    const int lane = threadIdx.x & 63;
    const int half = lane >> 5;        // which of 2 concurrent edges
    const int ql = lane & 31;          // uint2 column chunk (4 bf16 cols)
    const int n0 = blk * 8 + w * 2;    // wave owns nodes n0, n0+1 (both < NN: 6250*8=50000)
    const int n1 = n0 + 1;
    // 3 consecutive offs: [base0, end0==base1, end1]
    const int base0 = offs[n0], end0 = offs[n0 + 1], end1 = offs[n0 + 2];
    const int base1 = end0;
    const uint2* xw2 = (const uint2*)xfh;

    // issue both self rows + both first-chunk elist loads back-to-back
    uint2 self0 = xw2[(long)n0 * 32 + ql];
    uint2 self1 = xw2[(long)n1 * 32 + ql];
    int e0 = (base0 + lane < end0) ? elist[base0 + lane] : 0;
    int e1 = (base1 + lane < end1) ? elist[base1 + lane] : 0;

    float a0, a1, a2, a3, b0, b1, b2, b3;
    {
        float m = (half == 0) ? EPS1 : 0.f;
        a0 = m * us2f(self0.x); a1 = m * us2f(self0.x >> 16);
        a2 = m * us2f(self0.y); a3 = m * us2f(self0.y >> 16);
        b0 = m * us2f(self1.x); b1 = m * us2f(self1.x >> 16);
        b2 = m * us2f(self1.y); b3 = m * us2f(self1.y >> 16);
    }

    // ---- chunk 0 of both nodes, interleaved (covers deg <= 64) ----
    const int cnt0 = min(64, end0 - base0);
    const int cnt1 = min(64, end1 - base1);
    int j0 = 0, j1 = 0;
    while (j0 < cnt0 || j1 < cnt1) {
        int rem0 = cnt0 - j0, rem1 = cnt1 - j1;
        int g0 = 0, g1 = 0;
        uint2 p0[8], p1[8];
        GLOAD(p0, g0, e0, j0, rem0)
        GLOAD(p1, g1, e1, j1, rem1)
        GCONSUME(p0, g0, e0, j0, rem0, a0, a1, a2, a3)
        GCONSUME(p1, g1, e1, j1, rem1, b0, b1, b2, b3)
    }
    // ---- rare chunks beyond 64 edges: serial per node (v5 order) ----
    for (int i = base0 + 64; i < end0; i += 64) {
        int cnt = min(64, end0 - i);
        int e = (i + lane < end0) ? elist[i + lane] : 0;
        int j = 0;
        while (j < cnt) {
            int rem = cnt - j, g = 0;
            uint2 p[8];
            GLOAD(p, g, e, j, rem)
            GCONSUME(p, g, e, j, rem, a0, a1, a2, a3)
        }
    }
    for (int i = base1 + 64; i < end1; i += 64) {
        int cnt = min(64, end1 - i);
        int e = (i + lane < end1) ? elist[i + lane] : 0;
        int j = 0;
        while (j < cnt) {
            int rem = cnt - j, g = 0;
            uint2 p[8];
            GLOAD(p, g, e, j, rem)
            GCONSUME(p, g, e, j, rem, b0, b1, b2, b3)
        }
    }

    // combine the two halves (lane pair ql, ql+32 holds same cols)
    a0 += __shfl_xor(a0, 32); a1 += __shfl_xor(a1, 32);
    a2 += __shfl_xor(a2, 32); a3 += __shfl_xor(a3, 32);
    b0 += __shfl_xor(b0, 32); b1 += __shfl_xor(b1, 32);
    b2 += __shfl_xor(b2, 32); b3 += __shfl_xor(b3, 32);

    if (csB) {
        int c = ql * 4;
        float fac0 = (float)(end0 - base0) + EPS1;
        float fac1 = (float)(end1 - base1) + EPS1;
        #pragma unroll
        for (int k = 0; k < 4; k++) {
            float mu = csB[c + k] * (1.f / NN);
            float var = csB[128 + c + k] * (1.f / NN) - mu * mu;
            float sc = b2f(g2[c + k]) * rsqrtf(var + BN_EPS);
            float sh = b2f(be2[c + k]) - mu * sc;
            float* ap = (k == 0) ? &a0 : (k == 1) ? &a1 : (k == 2) ? &a2 : &a3;
            float* bp = (k == 0) ? &b0 : (k == 1) ? &b1 : (k == 2) ? &b2 : &b3;
            *ap = sc * (*ap) + fac0 * sh;
            *bp = sc * (*bp) + fac1 * sh;
        }
    }
    if (half == 0) {
        ((uint2*)aggh)[(long)n0 * 32 + ql] = make_uint2(pack2(a0, a1), pack2(a2, a3));
        ((uint2*)aggh)[(long)n1 * 32 + ql] = make_uint2(pack2(b0, b1), pack2(b2, b3));
    }
}

// standalone pool for the last layer
__launch_bounds__(256)
__global__ void k_pool(const bf16* __restrict__ xfh, const int* __restrict__ boffs,
                       const float* __restrict__ csB, const bf16* __restrict__ g2,
                       const bf16* __restrict__ be2, float* __restrict__ feats_blk) {
    pool_body(blockIdx.x, threadIdx.x, xfh, boffs, csB, g2, be2, feats_blk);
}

// ---- MFMA GEMM: 512 threads, 128 rows/block (391 blocks) ----
#define WS_S 136
__launch_bounds__(512)
__global__ void k_gemm_mfma(const bf16* __restrict__ A, const bf16* __restrict__ WT,
                            const bf16* __restrict__ bias,
                            const float* __restrict__ bn_cs, const bf16* __restrict__ bn_g,
                            const bf16* __restrict__ bn_be,
                            bf16* __restrict__ Out, float* __restrict__ cs_out,
                            float* cs_zero) {
    __shared__ short Ws[128 * WS_S];   // 34816 B (reused as C-staging)
    __shared__ float s_cs[256];
    __shared__ float s_sc[DD], s_sh[DD];
    const int t = threadIdx.x;
    const int row0 = blockIdx.x * 128;

    if (t < 256) {
        if (cs_zero && blockIdx.x == 0) cs_zero[t] = 0.f;
        s_cs[t] = 0.f;
    }
    if (bn_cs && t < DD) {
        float mu = bn_cs[t] * (1.f / NN);
        float var = bn_cs[128 + t] * (1.f / NN) - mu * mu;
        float sc = b2f(bn_g[t]) * rsqrtf(var + BN_EPS);
        s_sc[t] = sc;
        s_sh[t] = b2f(bn_be[t]) - mu * sc;
    }
    {   // stage WT (2048 uint4, 4 iters x 512 thr)
        const uint4* Wg = (const uint4*)WT;
        #pragma unroll
        for (int i = 0; i < 4; i++) {
            int idx = i * 512 + t;
            int row = idx >> 4, seg = idx & 15;
            *(uint4*)(&Ws[row * WS_S + seg * 8]) = Wg[idx];
        }
    }
    __syncthreads();

    const int w = t >> 6;          // wave 0..7 -> rows w*16..+15
    const int lane = t & 63;
    const int m = lane & 15;
    const int half = lane >> 4;
    const int r = row0 + w * 16 + m;

    short8 afrag[4];
    if (r < NN) {
        #pragma unroll
        for (int kk = 0; kk < 4; kk++)
            afrag[kk] = *(const short8*)(A + (long)r * DD + kk * 32 + half * 8);
        if (bn_cs) {
            #pragma unroll
            for (int kk = 0; kk < 4; kk++) {
                int c0 = kk * 32 + half * 8;
                uint4 p = *(uint4*)&afrag[kk];
                float v0 = us2f(p.x) * s_sc[c0+0] + s_sh[c0+0];
                float v1 = us2f(p.x >> 16) * s_sc[c0+1] + s_sh[c0+1];
                float v2 = us2f(p.y) * s_sc[c0+2] + s_sh[c0+2];
                float v3 = us2f(p.y >> 16) * s_sc[c0+3] + s_sh[c0+3];
                float v4 = us2f(p.z) * s_sc[c0+4] + s_sh[c0+4];
                float v5 = us2f(p.z >> 16) * s_sc[c0+5] + s_sh[c0+5];
                float v6 = us2f(p.w) * s_sc[c0+6] + s_sh[c0+6];
                float v7 = us2f(p.w >> 16) * s_sc[c0+7] + s_sh[c0+7];
                p.x = pack2(v0, v1); p.y = pack2(v2, v3);
                p.z = pack2(v4, v5); p.w = pack2(v6, v7);
                afrag[kk] = *(short8*)&p;
            }
        }
    } else {
        #pragma unroll
        for (int kk = 0; kk < 4; kk++) afrag[kk] = (short8){0,0,0,0,0,0,0,0};
    }

    f32x4 acc[8];
    #pragma unroll
    for (int nt = 0; nt < 8; nt++) acc[nt] = (f32x4){0.f, 0.f, 0.f, 0.f};

    #pragma unroll
    for (int nt = 0; nt < 8; nt++) {
        const short* wrow = &Ws[(nt * 16 + m) * WS_S + half * 8];
        #pragma unroll
        for (int kk = 0; kk < 4; kk++) {
            short8 b = *(const short8*)(wrow + kk * 32);
            acc[nt] = __builtin_amdgcn_mfma_f32_16x16x32_bf16(afrag[kk], b, acc[nt], 0, 0, 0);
        }
    }

    __syncthreads();               // all waves done reading Ws -> reuse as Cs
    short* Cs = Ws;
    #pragma unroll
    for (int nt = 0; nt < 8; nt++) {
        int col = nt * 16 + m;
        float bi = b2f(bias[col]);
        float ps = 0.f, pq = 0.f;
        #pragma unroll
        for (int reg = 0; reg < 4; reg++) {
            int rr = row0 + w * 16 + half * 4 + reg;
            float o = fmaxf(acc[nt][reg] + bi, 0.f);
            Cs[(w * 16 + half * 4 + reg) * WS_S + col] = f2bfs(o);
            if (rr < NN) { ps += o; pq += o * o; }
        }
        ps += __shfl_xor(ps, 16); ps += __shfl_xor(ps, 32);
        pq += __shfl_xor(pq, 16); pq += __shfl_xor(pq, 32);
        if (half == 0) {
            atomicAdd(&s_cs[col], ps);
            atomicAdd(&s_cs[128 + col], pq);
        }
    }
    __syncthreads();
    // vectorized store of the 128x128 tile
    #pragma unroll
    for (int i = 0; i < 4; i++) {
        int idx = i * 512 + t;
        int row = idx >> 4, seg = idx & 15;
        int rr = row0 + row;
        if (rr < NN)
            *(uint4*)(Out + (long)rr * DD + seg * 8) = *(uint4*)(&Cs[row * WS_S + seg * 8]);
    }
    if (t < 256) atomicAdd(&cs_out[t], s_cs[t]);
}

// parallel feature stats: 20 blocks x 256 thr (32 cols x 8 g-groups)
__launch_bounds__(256)
__global__ void k_feat_stats(const float* __restrict__ feats, const bf16* __restrict__ bn_g,
                             const bf16* __restrict__ bn_b, float* __restrict__ sc6,
                             float* __restrict__ sh6) {
    __shared__ float rs[8][32], rq[8][32];
    const int j0 = blockIdx.x * 32;
    const int jl = threadIdx.x & 31, gg = threadIdx.x >> 5;
    float s = 0.f, q = 0.f;
    for (int g = gg; g < NG; g += 8) {
        float v = feats[(long)g * (NB * DD) + j0 + jl];
        s += v; q += v * v;
    }
    rs[gg][jl] = s; rq[gg][jl] = q;
    __syncthreads();
    if (gg == 0) {
        #pragma unroll
        for (int k = 1; k < 8; k++) { s += rs[k][jl]; q += rq[k][jl]; }
        int j = j0 + jl;
        float mu = s / NG;
        float var = q / NG - mu * mu;
        float sc = b2f(bn_g[j]) * rsqrtf(var + BN_EPS);
        sc6[j] = sc;
        sh6[j] = b2f(bn_b[j]) - mu * sc;
    }
}

__launch_bounds__(128)
__global__ void k_head(const int* __restrict__ flags, const float* __restrict__ feats,
                       const float* __restrict__ sc6, const float* __restrict__ sh6,
                       const bf16* __restrict__ Wc1T, const bf16* __restrict__ bc1,
                       const bf16* __restrict__ Wc2, const bf16* __restrict__ bc2,
                       void* out) {
    __shared__ float fs[NB * DD];
    __shared__ float f1[DD];
    __shared__ float lg[NC + 2];
    const int g = blockIdx.x, t = threadIdx.x;
    for (int j = t; j < NB * DD; j += 128)
        fs[j] = feats[(long)g * (NB * DD) + j] * sc6[j] + sh6[j];
    __syncthreads();
    float acc = b2f(bc1[t]);
    {   // Wc1T row t: 640 contiguous bf16 = 80 x short8
        const short8* wr = (const short8*)(Wc1T + (long)t * (NB * DD));
        #pragma unroll 4
        for (int jb = 0; jb < 80; jb++) {
            short8 wv = wr[jb];
            uint4 p = *(uint4*)&wv;
            float4 f0 = *(const float4*)&fs[jb * 8];
            float4 f1v = *(const float4*)&fs[jb * 8 + 4];
            acc += f0.x * us2f(p.x) + f0.y * us2f(p.x >> 16)
                 + f0.z * us2f(p.y) + f0.w * us2f(p.y >> 16)
                 + f1v.x * us2f(p.z) + f1v.y * us2f(p.z >> 16)
                 + f1v.z * us2f(p.w) + f1v.w * us2f(p.w >> 16);
        }
    }
    f1[t] = fmaxf(acc, 0.f);
    __syncthreads();
    if (t < NC) {
        float a = b2f(bc2[t]);
        for (int k = 0; k < DD; k++) a += f1[k] * b2f(Wc2[k * NC + t]);
        lg[t] = a;
    }
    __syncthreads();
    if (t == 0) {
        float m = -1e30f;
        for (int c = 0; c < NC; c++) m = fmaxf(m, lg[c]);
        float s = 0.f;
        for (int c = 0; c < NC; c++) s += expf(lg[c] - m);
        lg[NC] = m + logf(s);
    }
    __syncthreads();
    if (t < NC) {
        float val = lg[t] - lg[NC];
        if (flags[0]) ((bf16*)out)[g * NC + t] = __float2bfloat16(val);
        else          ((float*)out)[g * NC + t] = val;
    }
}

extern "C" void kernel_launch(void* const* d_in, const int* in_sizes, int n_in,
                              void* d_out, int out_size, void* d_ws, size_t ws_size,
                              hipStream_t stream) {
    const void* x     = d_in[0];
    const int*  ei    = (const int*)d_in[1];
    const int*  batch = (const int*)d_in[2];

    float* ws    = (float*)d_ws;
    bf16*  aggh  = (bf16*)(ws + OFF_AGGH);
    bf16*  xfh   = (bf16*)(ws + OFF_XF);
    bf16*  h1h   = (bf16*)(ws + OFF_H1);
    float* feats = ws + OFF_FEATS;
    float* csA   = ws + OFF_CSA;
    float* csB   = ws + OFF_CSB;
    float* sc6   = ws + OFF_SC6;
    float* sh6   = ws + OFF_SH6;
    int*   flags = (int*)(ws + OFF_FLAGS);
    bf16*  pb    = (bf16*)(ws + OFF_PARAMS);
    int*   deg   = (int*)(ws + OFF_DEG);
    int*   offs  = (int*)(ws + OFF_OFFS);
    int*   elist = (int*)(ws + OFF_ELIST);
    int*   bdeg  = (int*)(ws + OFF_BDEG);
    int*   boffs = (int*)(ws + OFF_BOFFS);
    int*   rank  = (int*)(ws + OFF_RANK);
    int*   part  = (int*)(ws + OFF_PART);
    int*   erank = (int*)(ws + OFF_ERANK);

    bf16 *pW1T = pb + P_W1T, *pW2T = pb + P_W2T, *pWc1 = pb + P_WC1;
    bf16 *pb1 = pb + P_B1, *pg1 = pb + P_G1, *pbe1 = pb + P_BE1;
    bf16 *pb2 = pb + P_B2, *pg2 = pb + P_G2, *pbe2 = pb + P_BE2;
    bf16 *pbng = pb + P_BNG, *pbnb = pb + P_BNB;
    bf16 *pbc1 = pb + P_BC1, *pWc2 = pb + P_WC2, *pbc2 = pb + P_BC2;

    k_detect<<<1, 256, 0, stream>>>((const unsigned*)x, ei, batch, flags, bdeg);

    k_bhist<<<(NN + 255) / 256, 256, 0, stream>>>(flags, batch, bdeg, deg);
    k_bscan<<<1, 512, 0, stream>>>(bdeg, boffs);
    k_bplace<<<(NN + 255) / 256, 256, 0, stream>>>(flags, batch, bdeg, rank);

    SmallSrc ss;
    ss.s[0] = d_in[4];  ss.s[1] = d_in[5];  ss.s[2] = d_in[6];
    ss.s[3] = d_in[8];  ss.s[4] = d_in[9];  ss.s[5] = d_in[10];
    ss.s[6] = d_in[11]; ss.s[7] = d_in[12];
    ss.s[8] = d_in[14]; ss.s[9] = d_in[15]; ss.s[10] = d_in[16];
    k_convert_all<<<CVX_BLOCKS + CVP_BLOCKS, 256, 0, stream>>>(
        flags, x, rank, xfh, d_in[3], d_in[7], d_in[13], ss, pb);

    k_hist<<<NE / 256, 256, 0, stream>>>(flags, ei, rank, deg, erank);
    k_scan_part<<<49, 256, 0, stream>>>(deg, part);
    k_scan_apply<<<49, 256, 0, stream>>>(deg, part, offs);
    k_place<<<NE / 256, 256, 0, stream>>>(flags, ei, rank, offs, erank, elist);

    const int gemm_blocks = (NN + 127) / 128;   // 391
    for (int i = 0; i < NB; i++) {
        // gather(i) + pool(i-1) in one launch
        k_gather_pool<<<GB2 + NG, 256, 0, stream>>>(
            offs, elist, xfh, aggh,
            (i == 0) ? nullptr : csB,
            pg2 + (i - 1) * DD, pbe2 + (i - 1) * DD, csA,
            boffs, (i == 0) ? nullptr : feats + (i - 1) * DD);
        // GEMM1: aggh -> h1h, stats -> csA, zero csB
        k_gemm_mfma<<<gemm_blocks, 512, 0, stream>>>(aggh, pW1T + i * DD * DD, pb1 + i * DD,
                                                     nullptr, nullptr, nullptr,
                                                     h1h, csA, csB);
        // GEMM2: bn1(h1h) -> xfh, stats -> csB
        k_gemm_mfma<<<gemm_blocks, 512, 0, stream>>>(h1h, pW2T + i * DD * DD, pb2 + i * DD,
                                                     csA, pg1 + i * DD, pbe1 + i * DD,
                                                     xfh, csB, nullptr);
    }
    // final layer pool
    k_pool<<<NG, 256, 0, stream>>>(xfh, boffs, csB, pg2 + (NB - 1) * DD,
                                   pbe2 + (NB - 1) * DD, feats + (NB - 1) * DD);

    k_feat_stats<<<20, 256, 0, stream>>>(feats, pbng, pbnb, sc6, sh6);
    k_head<<<NG, 128, 0, stream>>>(flags, feats, sc6, sh6, pWc1, pbc1, pWc2, pbc2, d_out);
}